// Round 5
// baseline (3022.664 us; speedup 1.0000x reference)
//
#include <hip/hip_runtime.h>
#include <hip/hip_bf16.h>
#include <math.h>

// ---------------- problem constants ----------------
constexpr int NN   = 50000;        // nodes
constexpr int EE   = 400000;       // edges (before self loops)
constexpr int EP   = EE + NN;      // edges + self loops
constexpr int DIN  = 256;          // input dim
constexpr int M1   = 128;          // heads*H1
constexpr int F1   = 32;           // per-head dim layer 1
constexpr int H1N  = 4;            // heads layer 1
constexpr int M2   = 64;           // H2
constexpr int BP   = 4096;         // entity pairs
constexpr int DEC  = 512;          // decoder hidden
constexpr float SLOPE = 0.2f;

// output layout (flat, fp32)
constexpr int O_LOG    = 0;                      // [BP,2]
constexpr int O_RETOS  = 8192;                   // [NN,2]
constexpr int O_RETOSA = 108192;                 // [NN,2]
constexpr int O_X2     = 208192;                 // [NN,64]
constexpr int O_LOGITS = 3408192;                // [1,2NN]
constexpr int O_LOG1   = 3508192;                // [BP,2]

// ---------------- register-tiled GEMM + attention-score fusion ----------------
// Tile TN nodes into LDS; each thread owns 4 consecutive cols x NPT nodes.
// Per k: 1 float4 W load + NPT LDS broadcasts + 4*NPT FMAs.
template<int K, int M, int F, int TN, int BLK>
__global__ __launch_bounds__(BLK) void gemm_attn_t(
        const float* __restrict__ X, const float* __restrict__ Wm,
        const float* __restrict__ asrc, const float* __restrict__ adst,
        float* __restrict__ Hout, float* __restrict__ AS, float* __restrict__ AD){
    constexpr int CG  = M/4;        // col-groups (threads across M)
    constexpr int NG  = BLK/CG;     // node-groups
    constexpr int NPT = TN/NG;      // nodes per thread
    constexpr int H   = M/F;        // heads
    constexpr int RW  = F/4;        // shuffle-reduce width per head
    __shared__ float xs[TN*K];
    const int nb = blockIdx.x;
    const int t  = threadIdx.x;
    const int nbase0 = nb*TN;
    // ---- stage X tile (coalesced) ----
    if (nbase0 + TN <= NN){
        const float4* Xv = (const float4*)(X + (size_t)nbase0*K);
        float4* xv = (float4*)xs;
        #pragma unroll 4
        for (int i = t; i < TN*K/4; i += BLK) xv[i] = Xv[i];
    } else {
        for (int i = t; i < TN*K; i += BLK){
            size_t g = (size_t)nbase0*K + i;
            xs[i] = (g < (size_t)NN*K) ? X[g] : 0.f;
        }
    }
    __syncthreads();
    const int cg  = t % CG;
    const int ng  = t / CG;
    const int m4  = cg*4;
    const int nb0 = ng*NPT;
    float acc[NPT][4];
    #pragma unroll
    for (int j = 0; j < NPT; ++j){ acc[j][0]=0.f; acc[j][1]=0.f; acc[j][2]=0.f; acc[j][3]=0.f; }
    for (int k = 0; k < K; ++k){
        float4 wv = *(const float4*)(Wm + (size_t)k*M + m4);
        #pragma unroll
        for (int j = 0; j < NPT; ++j){
            float xv = xs[(nb0+j)*K + k];
            acc[j][0] += xv*wv.x; acc[j][1] += xv*wv.y;
            acc[j][2] += xv*wv.z; acc[j][3] += xv*wv.w;
        }
    }
    const float a0 = asrc[m4], a1 = asrc[m4+1], a2 = asrc[m4+2], a3 = asrc[m4+3];
    const float d0 = adst[m4], d1 = adst[m4+1], d2 = adst[m4+2], d3 = adst[m4+3];
    #pragma unroll
    for (int j = 0; j < NPT; ++j){
        int n = nbase0 + nb0 + j;
        bool ok = (n < NN);
        if (ok){
            float4 hv = make_float4(acc[j][0], acc[j][1], acc[j][2], acc[j][3]);
            *(float4*)(Hout + (size_t)n*M + m4) = hv;
        }
        float p1 = acc[j][0]*a0 + acc[j][1]*a1 + acc[j][2]*a2 + acc[j][3]*a3;
        float p2 = acc[j][0]*d0 + acc[j][1]*d1 + acc[j][2]*d2 + acc[j][3]*d3;
        #pragma unroll
        for (int o = RW/2; o > 0; o >>= 1){
            p1 += __shfl_down(p1, o, RW);
            p2 += __shfl_down(p2, o, RW);
        }
        if ((cg % RW) == 0 && ok){
            int h = cg / RW;
            AS[(size_t)n*H + h] = p1;
            AD[(size_t)n*H + h] = p2;
        }
    }
}

// per (edge, head): softmax denominator. Softmax WITHOUT max-subtraction:
// scores are O(+-10) so exp() is fp32-safe and alpha is mathematically identical.
__global__ void edge_denom(const int* __restrict__ esrc, const int* __restrict__ edst,
                           const float* __restrict__ AS, const float* __restrict__ AD,
                           float* __restrict__ denom, int H, int total){
    int j = blockIdx.x*blockDim.x + threadIdx.x;
    if (j >= total) return;
    int i = j / H, h = j - i*H;
    int s = (i < EE) ? esrc[i] : (i - EE);
    int d = (i < EE) ? edst[i] : (i - EE);
    float e = AS[(size_t)s*H + h] + AD[(size_t)d*H + h];
    e = (e >= 0.f) ? e : SLOPE*e;
    atomicAdd(&denom[(size_t)d*H + h], expf(e));
}

// one thread per (edge, col-quad): float4 gather of H, 4 atomic adds.
template<int M, int F>
__global__ void edge_scatter_v(const int* __restrict__ esrc, const int* __restrict__ edst,
                               const float* __restrict__ Hfeat,
                               const float* __restrict__ AS, const float* __restrict__ AD,
                               float* __restrict__ accum, int total){
    constexpr int Q = M/4;
    constexpr int H = M/F;
    int j = blockIdx.x*blockDim.x + threadIdx.x;
    if (j >= total) return;
    int i = j / Q, q = j - i*Q;
    int m = q*4, h = m / F;
    int s = (i < EE) ? esrc[i] : (i - EE);
    int d = (i < EE) ? edst[i] : (i - EE);
    float e = AS[(size_t)s*H + h] + AD[(size_t)d*H + h];
    e = (e >= 0.f) ? e : SLOPE*e;
    float w = expf(e);
    float4 hv = *(const float4*)(Hfeat + (size_t)s*M + m);
    float* ap = accum + (size_t)d*M + m;
    atomicAdd(ap+0, hv.x*w);
    atomicAdd(ap+1, hv.y*w);
    atomicAdd(ap+2, hv.z*w);
    atomicAdd(ap+3, hv.w*w);
}

// out = prelu(accum/(denom+eps) + b, p). Xout may alias accum.
__global__ void finalize_node(const float* accum, const float* denom,
                              const float* b, const float* p,
                              float* Xout, int M, int F, int total){
    int j = blockIdx.x*blockDim.x + threadIdx.x;
    if (j >= total) return;
    int n = j / M, m = j - n*M, h = m / F;
    float v = accum[j] / (denom[(size_t)n*(M/F) + h] + 1e-16f) + b[m];
    float pw = p[m];
    Xout[j] = (v >= 0.f) ? v : pw*v;
}

// column sums of x2 [NN,64] -> out[64]
__global__ void colsum(const float* __restrict__ X, float* __restrict__ out){
    __shared__ float red[256];
    const int c = blockIdx.x, t = threadIdx.x;
    float s = 0.f;
    for (int r = t; r < NN; r += 256) s += X[(size_t)r*64 + c];
    red[t] = s; __syncthreads();
    for (int o = 128; o > 0; o >>= 1){ if (t < o) red[t] += red[t+o]; __syncthreads(); }
    if (t == 0) out[c] = red[0];
}

// single block, 64 threads: summary vectors, bilinear Wc's, adv row-sums
__global__ void summary(const float* __restrict__ csum_o, const float* __restrict__ csum_a,
                        const float* __restrict__ mlpW, const float* __restrict__ mlpb,
                        const float* __restrict__ discW,
                        const float* __restrict__ advW, const float* __restrict__ advb,
                        float* __restrict__ Wc_o, float* __restrict__ Wc_a,
                        float* __restrict__ advRow, float* __restrict__ advbsum){
    __shared__ float s_o[64], s_a[64], h_o[64], h_a[64];
    const int t = threadIdx.x;
    s_o[t] = 1.f/(1.f + expf(-csum_o[t]/(float)NN));
    s_a[t] = 1.f/(1.f + expf(-csum_a[t]/(float)NN));
    __syncthreads();
    float ao = 0.f, aa = 0.f;
    for (int k = 0; k < 64; ++k){ float w = mlpW[k*64 + t]; ao += s_o[k]*w; aa += s_a[k]*w; }
    float bb = mlpb[t];
    h_o[t] = ao + bb; h_a[t] = aa + bb;
    __syncthreads();
    float wo = 0.f, wa = 0.f;
    for (int j = 0; j < 64; ++j){ float w = discW[t*64 + j]; wo += w*h_o[j]; wa += w*h_a[j]; }
    Wc_o[t] = wo; Wc_a[t] = wa;
    float ar = 0.f;
    for (int j = 0; j < 64; ++j) ar += advW[t*64 + j];
    advRow[t] = ar;
    float ab = advb[t];
    for (int o = 32; o > 0; o >>= 1) ab += __shfl_down(ab, o, 64);
    if (t == 0) advbsum[0] = ab;
}

// one wave (64 lanes) per node: 6 dot products + fp32 store of x2_o
__global__ void node_outputs(const float* __restrict__ x2o, const float* __restrict__ x2a,
                             const float* __restrict__ Wc_o, const float* __restrict__ Wc_a,
                             const float* __restrict__ advRow, const float* __restrict__ advbsum,
                             const float* __restrict__ discb,
                             float* __restrict__ out){
    const int n = blockIdx.x*4 + (threadIdx.x >> 6);
    const int l = threadIdx.x & 63;
    float xo = x2o[(size_t)n*64 + l], xa = x2a[(size_t)n*64 + l];
    float wo = Wc_o[l], wa = Wc_a[l], ar = advRow[l];
    float d1 = xo*wo, d2 = xa*wo, d3 = xa*wa, d4 = xo*wa, d5 = xo*ar, d6 = xa*ar;
    for (int o = 32; o > 0; o >>= 1){
        d1 += __shfl_down(d1, o, 64); d2 += __shfl_down(d2, o, 64);
        d3 += __shfl_down(d3, o, 64); d4 += __shfl_down(d4, o, 64);
        d5 += __shfl_down(d5, o, 64); d6 += __shfl_down(d6, o, 64);
    }
    out[O_X2 + (size_t)n*64 + l] = xo;
    if (l == 0){
        float db = discb[0];
        float ab = advbsum[0];
        out[O_RETOS  + n*2 + 0] = d1 + db;
        out[O_RETOS  + n*2 + 1] = d2 + db;
        out[O_RETOSA + n*2 + 0] = d3 + db;
        out[O_RETOSA + n*2 + 1] = d4 + db;
        out[O_LOGITS + n]       = d5 + ab;
        out[O_LOGITS + NN + n]  = d6 + ab;
    }
}

// fh = relu([x2[i0], x2[i1]] @ fW1 + fb1) : block per pair, 256 threads
__global__ void decoder1(const float* __restrict__ x2o, const int* __restrict__ idxArr,
                         const float* __restrict__ fW1, const float* __restrict__ fb1,
                         float* __restrict__ fh){
    __shared__ float e[128];
    const int b = blockIdx.x, t = threadIdx.x;
    const int i0 = idxArr[b], i1 = idxArr[BP + b];
    if (t < 64)        e[t] = x2o[(size_t)i0*64 + t];
    else if (t < 128)  e[t] = x2o[(size_t)i1*64 + (t - 64)];
    __syncthreads();
    for (int mm = t; mm < DEC; mm += 256){
        float acc = 0.f;
        #pragma unroll 8
        for (int k = 0; k < 128; ++k) acc += e[k] * fW1[(size_t)k*DEC + mm];
        acc += fb1[mm];
        fh[(size_t)b*DEC + mm] = (acc > 0.f) ? acc : 0.f;
    }
}

// log / log1 heads: one wave per pair
__global__ void decoder2(const float* __restrict__ fh,
                         const float* __restrict__ fW2, const float* __restrict__ fb2,
                         const float* __restrict__ fW3, const float* __restrict__ fb3,
                         float* __restrict__ out){
    const int b = blockIdx.x, t = threadIdx.x;
    float a0 = 0.f, a1 = 0.f, c0 = 0.f, c1 = 0.f;
    for (int m = t; m < DEC; m += 64){
        float v = fh[(size_t)b*DEC + m];
        a0 += v*fW2[m*2 + 0]; a1 += v*fW2[m*2 + 1];
        c0 += v*fW3[m*2 + 0]; c1 += v*fW3[m*2 + 1];
    }
    for (int o = 32; o > 0; o >>= 1){
        a0 += __shfl_down(a0, o, 64); a1 += __shfl_down(a1, o, 64);
        c0 += __shfl_down(c0, o, 64); c1 += __shfl_down(c1, o, 64);
    }
    if (t == 0){
        out[O_LOG  + b*2 + 0] = a0 + fb2[0];
        out[O_LOG  + b*2 + 1] = a1 + fb2[1];
        out[O_LOG1 + b*2 + 0] = c0 + fb3[0];
        out[O_LOG1 + b*2 + 1] = c1 + fb3[1];
    }
}

extern "C" void kernel_launch(void* const* d_in, const int* in_sizes, int n_in,
                              void* d_out, int out_size, void* d_ws, size_t ws_size,
                              hipStream_t stream){
    const float* x_o    = (const float*)d_in[0];
    const float* x_a    = (const float*)d_in[1];
    const int*   edge   = (const int*)d_in[2];
    const int*   idxp   = (const int*)d_in[3];
    const float* W1     = (const float*)d_in[4];
    const float* a_src1 = (const float*)d_in[5];
    const float* a_dst1 = (const float*)d_in[6];
    const float* b1     = (const float*)d_in[7];
    const float* p1     = (const float*)d_in[8];
    const float* W2     = (const float*)d_in[9];
    const float* a_src2 = (const float*)d_in[10];
    const float* a_dst2 = (const float*)d_in[11];
    const float* b2     = (const float*)d_in[12];
    const float* p2     = (const float*)d_in[13];
    const float* mlpW   = (const float*)d_in[14];
    const float* mlpb   = (const float*)d_in[15];
    const float* discW  = (const float*)d_in[16];
    const float* discb  = (const float*)d_in[17];
    const float* advW   = (const float*)d_in[18];
    const float* advb   = (const float*)d_in[19];
    const float* fW1    = (const float*)d_in[20];
    const float* fb1    = (const float*)d_in[21];
    const float* fW2    = (const float*)d_in[22];
    const float* fb2    = (const float*)d_in[23];
    const float* fW3    = (const float*)d_in[24];
    const float* fb3    = (const float*)d_in[25];

    const int* esrc = edge;
    const int* edst = edge + EE;

    // workspace carve-up (fp32), ~78 MB total
    float* w = (float*)d_ws;
    size_t off = 0;
    auto alloc = [&](size_t nfloats){ float* p = w + off; off += nfloats; return p; };
    float* accum = alloc((size_t)NN * M1);   // scatter accumulator; x1b aliases (in-place)
    float* hbuf  = alloc((size_t)NN * M1);   // H = X@W; fh aliases after encoders
    float* asb   = alloc((size_t)NN * H1N);
    float* adb   = alloc((size_t)NN * H1N);
    float* denom = alloc((size_t)NN * H1N);
    float* x2o   = alloc((size_t)NN * M2);
    float* x2a   = alloc((size_t)NN * M2);
    float* smallb= alloc(512);
    float* x1b    = accum;                 // layer-1 finalize runs in-place
    float* fh     = hbuf;                  // decoder scratch after encoders done
    float* csum_o = smallb;       float* csum_a = smallb + 64;
    float* Wc_o   = smallb + 128; float* Wc_a   = smallb + 192;
    float* advRow = smallb + 256; float* advbs  = smallb + 320;

    float* out = (float*)d_out;

    constexpr int TN = 32;
    const int gnodes = (NN + TN - 1) / TN;

    auto run_encoder = [&](const float* xin, float* x2out){
        // ---- layer 1: D=256 -> 4 heads x 32 ----
        gemm_attn_t<DIN, M1, F1, TN, 256><<<gnodes, 256, 0, stream>>>(
            xin, W1, a_src1, a_dst1, hbuf, asb, adb);
        hipMemsetAsync(denom, 0, (size_t)NN*H1N*sizeof(float), stream);
        hipMemsetAsync(accum, 0, (size_t)NN*M1*sizeof(float), stream);
        edge_denom<<<(EP*H1N + 255)/256, 256, 0, stream>>>(esrc, edst, asb, adb, denom, H1N, EP*H1N);
        {
            int tot = EP * (M1/4);   // 14.4M
            edge_scatter_v<M1, F1><<<(tot + 255)/256, 256, 0, stream>>>(
                esrc, edst, hbuf, asb, adb, accum, tot);
        }
        finalize_node<<<(NN*M1 + 255)/256, 256, 0, stream>>>(accum, denom, b1, p1,
                                                             x1b, M1, F1, NN*M1);

        // ---- layer 2: 128 -> 64, 1 head ----
        gemm_attn_t<M1, M2, M2, TN, 256><<<gnodes, 256, 0, stream>>>(
            x1b, W2, a_src2, a_dst2, hbuf, asb, adb);
        hipMemsetAsync(denom, 0, (size_t)NN*sizeof(float), stream);
        hipMemsetAsync(accum, 0, (size_t)NN*M2*sizeof(float), stream);
        edge_denom<<<(EP + 255)/256, 256, 0, stream>>>(esrc, edst, asb, adb, denom, 1, EP);
        {
            int tot = EP * (M2/4);   // 7.2M
            edge_scatter_v<M2, M2><<<(tot + 255)/256, 256, 0, stream>>>(
                esrc, edst, hbuf, asb, adb, accum, tot);
        }
        finalize_node<<<(NN*M2 + 255)/256, 256, 0, stream>>>(accum, denom, b2, p2,
                                                             x2out, M2, M2, NN*M2);
    };

    run_encoder(x_o, x2o);
    run_encoder(x_a, x2a);

    colsum<<<64, 256, 0, stream>>>(x2o, csum_o);
    colsum<<<64, 256, 0, stream>>>(x2a, csum_a);
    summary<<<1, 64, 0, stream>>>(csum_o, csum_a, mlpW, mlpb, discW, advW, advb,
                                  Wc_o, Wc_a, advRow, advbs);
    node_outputs<<<NN/4, 256, 0, stream>>>(x2o, x2a, Wc_o, Wc_a, advRow, advbs, discb, out);
    decoder1<<<BP, 256, 0, stream>>>(x2o, idxp, fW1, fb1, fh);
    decoder2<<<BP, 64, 0, stream>>>(fh, fW2, fb2, fW3, fb3, out);
}

// Round 6
// 922.673 us; speedup vs baseline: 3.2760x; 3.2760x over previous
//
#include <hip/hip_runtime.h>
#include <hip/hip_bf16.h>
#include <math.h>

// ---------------- problem constants ----------------
constexpr int NN   = 50000;        // nodes
constexpr int EE   = 400000;       // edges (before self loops)
constexpr int EP   = EE + NN;      // edges + self loops
constexpr int DIN  = 256;          // input dim
constexpr int M1   = 128;          // heads*H1
constexpr int F1   = 32;           // per-head dim layer 1
constexpr int H1N  = 4;            // heads layer 1
constexpr int M2   = 64;           // H2
constexpr int BP   = 4096;         // entity pairs
constexpr int DEC  = 512;          // decoder hidden
constexpr float SLOPE = 0.2f;

// output layout (flat, fp32)
constexpr int O_LOG    = 0;                      // [BP,2]
constexpr int O_RETOS  = 8192;                   // [NN,2]
constexpr int O_RETOSA = 108192;                 // [NN,2]
constexpr int O_X2     = 208192;                 // [NN,64]
constexpr int O_LOGITS = 3408192;                // [1,2NN]
constexpr int O_LOG1   = 3508192;                // [BP,2]

// ---------------- CSR build (by destination), done once per launch ----------------
__global__ void zero_int(int* p, int n){
    int i = blockIdx.x*blockDim.x + threadIdx.x;
    if (i < n) p[i] = 0;
}

__global__ void hist_dst(const int* __restrict__ edst, int* __restrict__ cnt){
    int i = blockIdx.x*blockDim.x + threadIdx.x;
    if (i < EE) atomicAdd(&cnt[edst[i]], 1);
}

// single-block exclusive scan over NN counters -> row[], cursor[] (copies)
__global__ __launch_bounds__(1024) void scan_nodes(const int* __restrict__ cnt,
                                                   int* __restrict__ row,
                                                   int* __restrict__ cursor){
    __shared__ int part[1024];
    const int T = 1024, per = (NN + T - 1)/T;
    const int t = threadIdx.x;
    const int base = t*per;
    int s = 0;
    for (int i = 0; i < per; ++i){ int idx = base + i; if (idx < NN) s += cnt[idx]; }
    part[t] = s; __syncthreads();
    for (int o = 1; o < T; o <<= 1){
        int v = (t >= o) ? part[t-o] : 0;
        __syncthreads();
        part[t] += v;
        __syncthreads();
    }
    int run = (t == 0) ? 0 : part[t-1];
    for (int i = 0; i < per; ++i){
        int idx = base + i;
        if (idx < NN){ row[idx] = run; cursor[idx] = run; run += cnt[idx]; }
    }
    if (t == T-1) row[NN] = run;   // == EE
}

__global__ void fill_csr(const int* __restrict__ esrc, const int* __restrict__ edst,
                         int* __restrict__ cursor, int* __restrict__ adj){
    int i = blockIdx.x*blockDim.x + threadIdx.x;
    if (i >= EE) return;
    int d = edst[i];
    int slot = atomicAdd(&cursor[d], 1);
    adj[slot] = esrc[i];
}

// ---------------- register-tiled GEMM + attention-score fusion ----------------
template<int K, int M, int F, int TN, int BLK>
__global__ __launch_bounds__(BLK) void gemm_attn_t(
        const float* __restrict__ X, const float* __restrict__ Wm,
        const float* __restrict__ asrc, const float* __restrict__ adst,
        float* __restrict__ Hout, float* __restrict__ AS, float* __restrict__ AD){
    constexpr int CG  = M/4;        // col-groups (threads across M)
    constexpr int NG  = BLK/CG;     // node-groups
    constexpr int NPT = TN/NG;      // nodes per thread
    constexpr int H   = M/F;        // heads
    constexpr int RW  = F/4;        // shuffle-reduce width per head
    __shared__ float xs[TN*K];
    const int nb = blockIdx.x;
    const int t  = threadIdx.x;
    const int nbase0 = nb*TN;
    if (nbase0 + TN <= NN){
        const float4* Xv = (const float4*)(X + (size_t)nbase0*K);
        float4* xv = (float4*)xs;
        #pragma unroll 4
        for (int i = t; i < TN*K/4; i += BLK) xv[i] = Xv[i];
    } else {
        for (int i = t; i < TN*K; i += BLK){
            size_t g = (size_t)nbase0*K + i;
            xs[i] = (g < (size_t)NN*K) ? X[g] : 0.f;
        }
    }
    __syncthreads();
    const int cg  = t % CG;
    const int ng  = t / CG;
    const int m4  = cg*4;
    const int nb0 = ng*NPT;
    float acc[NPT][4];
    #pragma unroll
    for (int j = 0; j < NPT; ++j){ acc[j][0]=0.f; acc[j][1]=0.f; acc[j][2]=0.f; acc[j][3]=0.f; }
    for (int k = 0; k < K; ++k){
        float4 wv = *(const float4*)(Wm + (size_t)k*M + m4);
        #pragma unroll
        for (int j = 0; j < NPT; ++j){
            float xv = xs[(nb0+j)*K + k];
            acc[j][0] += xv*wv.x; acc[j][1] += xv*wv.y;
            acc[j][2] += xv*wv.z; acc[j][3] += xv*wv.w;
        }
    }
    const float a0 = asrc[m4], a1 = asrc[m4+1], a2 = asrc[m4+2], a3 = asrc[m4+3];
    const float d0 = adst[m4], d1 = adst[m4+1], d2 = adst[m4+2], d3 = adst[m4+3];
    #pragma unroll
    for (int j = 0; j < NPT; ++j){
        int n = nbase0 + nb0 + j;
        bool ok = (n < NN);
        if (ok){
            float4 hv = make_float4(acc[j][0], acc[j][1], acc[j][2], acc[j][3]);
            *(float4*)(Hout + (size_t)n*M + m4) = hv;
        }
        float p1 = acc[j][0]*a0 + acc[j][1]*a1 + acc[j][2]*a2 + acc[j][3]*a3;
        float p2 = acc[j][0]*d0 + acc[j][1]*d1 + acc[j][2]*d2 + acc[j][3]*d3;
        #pragma unroll
        for (int o = RW/2; o > 0; o >>= 1){
            p1 += __shfl_down(p1, o, RW);
            p2 += __shfl_down(p2, o, RW);
        }
        if ((cg % RW) == 0 && ok){
            int h = cg / RW;
            AS[(size_t)n*H + h] = p1;
            AD[(size_t)n*H + h] = p2;
        }
    }
}

// ---------------- atomic-free GAT aggregation ----------------
// One block (M threads) per dst node. Walks the dst's CSR in-edge list plus the
// self loop. adj[j] is a block-uniform broadcast load; H[src] rows are coalesced.
// Softmax without max-subtraction (scores O(+-10), exp fp32-safe; alpha identical:
// the max cancels). Denominator accumulated redundantly per thread; PReLU+bias
// epilogue fused (was finalize_node).
template<int M, int F>
__global__ __launch_bounds__(M) void gat_aggregate(
        const int* __restrict__ row, const int* __restrict__ adj,
        const float* __restrict__ Hfeat,
        const float* __restrict__ AS, const float* __restrict__ AD,
        const float* __restrict__ b, const float* __restrict__ p,
        float* __restrict__ Xout){
    constexpr int NH = M/F;
    const int d = blockIdx.x;
    const int m = threadIdx.x;
    const int h = m / F;
    const float ad = AD[(size_t)d*NH + h];
    float acc = 0.f, den = 0.f;
    {   // self loop
        float e = AS[(size_t)d*NH + h] + ad;
        e = (e >= 0.f) ? e : SLOPE*e;
        float wgt = expf(e);
        acc += Hfeat[(size_t)d*M + m] * wgt;
        den += wgt;
    }
    const int beg = row[d], end = row[d+1];
    for (int j = beg; j < end; ++j){
        int s = adj[j];
        float e = AS[(size_t)s*NH + h] + ad;
        e = (e >= 0.f) ? e : SLOPE*e;
        float wgt = expf(e);
        acc += Hfeat[(size_t)s*M + m] * wgt;
        den += wgt;
    }
    float v = acc/(den + 1e-16f) + b[m];
    float pw = p[m];
    Xout[(size_t)d*M + m] = (v >= 0.f) ? v : pw*v;
}

// column sums of x2 [NN,64] -> out[64]
__global__ void colsum(const float* __restrict__ X, float* __restrict__ out){
    __shared__ float red[256];
    const int c = blockIdx.x, t = threadIdx.x;
    float s = 0.f;
    for (int r = t; r < NN; r += 256) s += X[(size_t)r*64 + c];
    red[t] = s; __syncthreads();
    for (int o = 128; o > 0; o >>= 1){ if (t < o) red[t] += red[t+o]; __syncthreads(); }
    if (t == 0) out[c] = red[0];
}

// single block, 64 threads: summary vectors, bilinear Wc's, adv row-sums
__global__ void summary(const float* __restrict__ csum_o, const float* __restrict__ csum_a,
                        const float* __restrict__ mlpW, const float* __restrict__ mlpb,
                        const float* __restrict__ discW,
                        const float* __restrict__ advW, const float* __restrict__ advb,
                        float* __restrict__ Wc_o, float* __restrict__ Wc_a,
                        float* __restrict__ advRow, float* __restrict__ advbsum){
    __shared__ float s_o[64], s_a[64], h_o[64], h_a[64];
    const int t = threadIdx.x;
    s_o[t] = 1.f/(1.f + expf(-csum_o[t]/(float)NN));
    s_a[t] = 1.f/(1.f + expf(-csum_a[t]/(float)NN));
    __syncthreads();
    float ao = 0.f, aa = 0.f;
    for (int k = 0; k < 64; ++k){ float w = mlpW[k*64 + t]; ao += s_o[k]*w; aa += s_a[k]*w; }
    float bb = mlpb[t];
    h_o[t] = ao + bb; h_a[t] = aa + bb;
    __syncthreads();
    float wo = 0.f, wa = 0.f;
    for (int j = 0; j < 64; ++j){ float w = discW[t*64 + j]; wo += w*h_o[j]; wa += w*h_a[j]; }
    Wc_o[t] = wo; Wc_a[t] = wa;
    float ar = 0.f;
    for (int j = 0; j < 64; ++j) ar += advW[t*64 + j];
    advRow[t] = ar;
    float ab = advb[t];
    for (int o = 32; o > 0; o >>= 1) ab += __shfl_down(ab, o, 64);
    if (t == 0) advbsum[0] = ab;
}

// one wave (64 lanes) per node: 6 dot products + fp32 store of x2_o
__global__ void node_outputs(const float* __restrict__ x2o, const float* __restrict__ x2a,
                             const float* __restrict__ Wc_o, const float* __restrict__ Wc_a,
                             const float* __restrict__ advRow, const float* __restrict__ advbsum,
                             const float* __restrict__ discb,
                             float* __restrict__ out){
    const int n = blockIdx.x*4 + (threadIdx.x >> 6);
    const int l = threadIdx.x & 63;
    float xo = x2o[(size_t)n*64 + l], xa = x2a[(size_t)n*64 + l];
    float wo = Wc_o[l], wa = Wc_a[l], ar = advRow[l];
    float d1 = xo*wo, d2 = xa*wo, d3 = xa*wa, d4 = xo*wa, d5 = xo*ar, d6 = xa*ar;
    for (int o = 32; o > 0; o >>= 1){
        d1 += __shfl_down(d1, o, 64); d2 += __shfl_down(d2, o, 64);
        d3 += __shfl_down(d3, o, 64); d4 += __shfl_down(d4, o, 64);
        d5 += __shfl_down(d5, o, 64); d6 += __shfl_down(d6, o, 64);
    }
    out[O_X2 + (size_t)n*64 + l] = xo;
    if (l == 0){
        float db = discb[0];
        float ab = advbsum[0];
        out[O_RETOS  + n*2 + 0] = d1 + db;
        out[O_RETOS  + n*2 + 1] = d2 + db;
        out[O_RETOSA + n*2 + 0] = d3 + db;
        out[O_RETOSA + n*2 + 1] = d4 + db;
        out[O_LOGITS + n]       = d5 + ab;
        out[O_LOGITS + NN + n]  = d6 + ab;
    }
}

// fh = relu([x2[i0], x2[i1]] @ fW1 + fb1) : block per pair, 256 threads
__global__ void decoder1(const float* __restrict__ x2o, const int* __restrict__ idxArr,
                         const float* __restrict__ fW1, const float* __restrict__ fb1,
                         float* __restrict__ fh){
    __shared__ float e[128];
    const int b = blockIdx.x, t = threadIdx.x;
    const int i0 = idxArr[b], i1 = idxArr[BP + b];
    if (t < 64)        e[t] = x2o[(size_t)i0*64 + t];
    else if (t < 128)  e[t] = x2o[(size_t)i1*64 + (t - 64)];
    __syncthreads();
    for (int mm = t; mm < DEC; mm += 256){
        float acc = 0.f;
        #pragma unroll 8
        for (int k = 0; k < 128; ++k) acc += e[k] * fW1[(size_t)k*DEC + mm];
        acc += fb1[mm];
        fh[(size_t)b*DEC + mm] = (acc > 0.f) ? acc : 0.f;
    }
}

// log / log1 heads: one wave per pair
__global__ void decoder2(const float* __restrict__ fh,
                         const float* __restrict__ fW2, const float* __restrict__ fb2,
                         const float* __restrict__ fW3, const float* __restrict__ fb3,
                         float* __restrict__ out){
    const int b = blockIdx.x, t = threadIdx.x;
    float a0 = 0.f, a1 = 0.f, c0 = 0.f, c1 = 0.f;
    for (int m = t; m < DEC; m += 64){
        float v = fh[(size_t)b*DEC + m];
        a0 += v*fW2[m*2 + 0]; a1 += v*fW2[m*2 + 1];
        c0 += v*fW3[m*2 + 0]; c1 += v*fW3[m*2 + 1];
    }
    for (int o = 32; o > 0; o >>= 1){
        a0 += __shfl_down(a0, o, 64); a1 += __shfl_down(a1, o, 64);
        c0 += __shfl_down(c0, o, 64); c1 += __shfl_down(c1, o, 64);
    }
    if (t == 0){
        out[O_LOG  + b*2 + 0] = a0 + fb2[0];
        out[O_LOG  + b*2 + 1] = a1 + fb2[1];
        out[O_LOG1 + b*2 + 0] = c0 + fb3[0];
        out[O_LOG1 + b*2 + 1] = c1 + fb3[1];
    }
}

extern "C" void kernel_launch(void* const* d_in, const int* in_sizes, int n_in,
                              void* d_out, int out_size, void* d_ws, size_t ws_size,
                              hipStream_t stream){
    const float* x_o    = (const float*)d_in[0];
    const float* x_a    = (const float*)d_in[1];
    const int*   edge   = (const int*)d_in[2];
    const int*   idxp   = (const int*)d_in[3];
    const float* W1     = (const float*)d_in[4];
    const float* a_src1 = (const float*)d_in[5];
    const float* a_dst1 = (const float*)d_in[6];
    const float* b1     = (const float*)d_in[7];
    const float* p1     = (const float*)d_in[8];
    const float* W2     = (const float*)d_in[9];
    const float* a_src2 = (const float*)d_in[10];
    const float* a_dst2 = (const float*)d_in[11];
    const float* b2     = (const float*)d_in[12];
    const float* p2     = (const float*)d_in[13];
    const float* mlpW   = (const float*)d_in[14];
    const float* mlpb   = (const float*)d_in[15];
    const float* discW  = (const float*)d_in[16];
    const float* discb  = (const float*)d_in[17];
    const float* advW   = (const float*)d_in[18];
    const float* advb   = (const float*)d_in[19];
    const float* fW1    = (const float*)d_in[20];
    const float* fb1    = (const float*)d_in[21];
    const float* fW2    = (const float*)d_in[22];
    const float* fb2    = (const float*)d_in[23];
    const float* fW3    = (const float*)d_in[24];
    const float* fb3    = (const float*)d_in[25];

    const int* esrc = edge;
    const int* edst = edge + EE;

    // workspace carve-up (fp32), ~80 MB total
    float* w = (float*)d_ws;
    size_t off = 0;
    auto alloc = [&](size_t nfloats){ float* p = w + off; off += nfloats; return p; };
    float* hbuf  = alloc((size_t)NN * M1);   // H = X@W
    float* x1b   = alloc((size_t)NN * M1);   // layer-1 output; fh aliases after encoders
    float* asb   = alloc((size_t)NN * H1N);
    float* adb   = alloc((size_t)NN * H1N);
    float* x2o   = alloc((size_t)NN * M2);
    float* x2a   = alloc((size_t)NN * M2);
    int*   cnt   = (int*)alloc(NN);
    int*   row   = (int*)alloc(NN + 1);
    int*   cursor= (int*)alloc(NN);
    int*   adj   = (int*)alloc(EE);
    float* smallb= alloc(512);
    float* fh     = x1b;                   // decoder scratch after encoders done
    float* csum_o = smallb;       float* csum_a = smallb + 64;
    float* Wc_o   = smallb + 128; float* Wc_a   = smallb + 192;
    float* advRow = smallb + 256; float* advbs  = smallb + 320;

    float* out = (float*)d_out;

    // ---- CSR build (once; reused by all 4 aggregations) ----
    zero_int<<<(NN + 255)/256, 256, 0, stream>>>(cnt, NN);
    hist_dst<<<(EE + 255)/256, 256, 0, stream>>>(edst, cnt);
    scan_nodes<<<1, 1024, 0, stream>>>(cnt, row, cursor);
    fill_csr<<<(EE + 255)/256, 256, 0, stream>>>(esrc, edst, cursor, adj);

    constexpr int TN = 32;
    const int gnodes = (NN + TN - 1) / TN;

    auto run_encoder = [&](const float* xin, float* x2out){
        // ---- layer 1: D=256 -> 4 heads x 32 ----
        gemm_attn_t<DIN, M1, F1, TN, 256><<<gnodes, 256, 0, stream>>>(
            xin, W1, a_src1, a_dst1, hbuf, asb, adb);
        gat_aggregate<M1, F1><<<NN, M1, 0, stream>>>(
            row, adj, hbuf, asb, adb, b1, p1, x1b);

        // ---- layer 2: 128 -> 64, 1 head ----
        gemm_attn_t<M1, M2, M2, TN, 256><<<gnodes, 256, 0, stream>>>(
            x1b, W2, a_src2, a_dst2, hbuf, asb, adb);
        gat_aggregate<M2, M2><<<NN, M2, 0, stream>>>(
            row, adj, hbuf, asb, adb, b2, p2, x2out);
    };

    run_encoder(x_o, x2o);
    run_encoder(x_a, x2a);

    colsum<<<64, 256, 0, stream>>>(x2o, csum_o);
    colsum<<<64, 256, 0, stream>>>(x2a, csum_a);
    summary<<<1, 64, 0, stream>>>(csum_o, csum_a, mlpW, mlpb, discW, advW, advb,
                                  Wc_o, Wc_a, advRow, advbs);
    node_outputs<<<NN/4, 256, 0, stream>>>(x2o, x2a, Wc_o, Wc_a, advRow, advbs, discb, out);
    decoder1<<<BP, 256, 0, stream>>>(x2o, idxp, fW1, fb1, fh);
    decoder2<<<BP, 64, 0, stream>>>(fh, fW2, fb2, fW3, fb3, out);
}

// Round 7
// 812.960 us; speedup vs baseline: 3.7181x; 1.1350x over previous
//
#include <hip/hip_runtime.h>
#include <hip/hip_bf16.h>
#include <math.h>

// ---------------- problem constants ----------------
constexpr int NN   = 50000;        // nodes
constexpr int EE   = 400000;       // edges (before self loops)
constexpr int EP   = EE + NN;      // edges + self loops
constexpr int DIN  = 256;          // input dim
constexpr int M1   = 128;          // heads*H1
constexpr int F1   = 32;           // per-head dim layer 1
constexpr int H1N  = 4;            // heads layer 1
constexpr int M2   = 64;           // H2
constexpr int BP   = 4096;         // entity pairs
constexpr int DEC  = 512;          // decoder hidden
constexpr float SLOPE = 0.2f;

// output layout (flat, fp32)
constexpr int O_LOG    = 0;                      // [BP,2]
constexpr int O_RETOS  = 8192;                   // [NN,2]
constexpr int O_RETOSA = 108192;                 // [NN,2]
constexpr int O_X2     = 208192;                 // [NN,64]
constexpr int O_LOGITS = 3408192;                // [1,2NN]
constexpr int O_LOG1   = 3508192;                // [BP,2]

constexpr int SCAN_NB = (NN + 1023) / 1024;      // 49 scan blocks

// ---------------- CSR build (by destination), done once per launch ----------------
__global__ void hist_dst(const int* __restrict__ edst, int* __restrict__ cnt){
    int i = blockIdx.x*blockDim.x + threadIdx.x;
    if (i < EE) atomicAdd(&cnt[edst[i]], 1);
}

// A: per-block (1024 elems) exclusive scan + block totals. Coalesced, parallel.
__global__ __launch_bounds__(1024) void scan_blk(const int* __restrict__ cnt,
                                                 int* __restrict__ rowex,
                                                 int* __restrict__ bsum){
    __shared__ int wsum[16];
    const int t = threadIdx.x;
    const int idx = blockIdx.x*1024 + t;
    const int lane = t & 63, wid = t >> 6;
    int v = (idx < NN) ? cnt[idx] : 0;
    int s = v;
    #pragma unroll
    for (int o = 1; o < 64; o <<= 1){
        int u = __shfl_up(s, o, 64);
        if (lane >= o) s += u;
    }
    if (lane == 63) wsum[wid] = s;
    __syncthreads();
    if (wid == 0){
        int ws = (lane < 16) ? wsum[lane] : 0;
        #pragma unroll
        for (int o = 1; o < 16; o <<= 1){
            int u = __shfl_up(ws, o, 64);
            if (lane >= o) ws += u;
        }
        if (lane < 16) wsum[lane] = ws;
    }
    __syncthreads();
    int base = (wid > 0) ? wsum[wid-1] : 0;
    int incl = base + s;
    if (idx < NN) rowex[idx] = incl - v;        // exclusive within block
    if (t == 1023) bsum[blockIdx.x] = incl;     // block total
}

// B: one wave scans the block totals in-place (exclusive).
__global__ void scan_bsum(int* __restrict__ bsum, int nb){
    const int lane = threadIdx.x;
    int v = (lane < nb) ? bsum[lane] : 0;
    int s = v;
    #pragma unroll
    for (int o = 1; o < 64; o <<= 1){
        int u = __shfl_up(s, o, 64);
        if (lane >= o) s += u;
    }
    if (lane < nb) bsum[lane] = s - v;
}

// C: add block offsets; copy to cursor; row[NN] = EE (total is static).
__global__ void scan_fix(int* __restrict__ row, const int* __restrict__ bsum,
                         int* __restrict__ cursor){
    int idx = blockIdx.x*blockDim.x + threadIdx.x;
    if (idx < NN){
        int r = row[idx] + bsum[idx >> 10];
        row[idx] = r;
        cursor[idx] = r;
    }
    if (idx == 0) row[NN] = EE;
}

__global__ void fill_csr(const int* __restrict__ esrc, const int* __restrict__ edst,
                         int* __restrict__ cursor, int* __restrict__ adj){
    int i = blockIdx.x*blockDim.x + threadIdx.x;
    if (i >= EE) return;
    int d = edst[i];
    int slot = atomicAdd(&cursor[d], 1);
    adj[slot] = esrc[i];
}

// ---------------- register-tiled GEMM + attention-score fusion ----------------
template<int K, int M, int F, int TN, int BLK>
__global__ __launch_bounds__(BLK) void gemm_attn_t(
        const float* __restrict__ X, const float* __restrict__ Wm,
        const float* __restrict__ asrc, const float* __restrict__ adst,
        float* __restrict__ Hout, float* __restrict__ AS, float* __restrict__ AD){
    constexpr int CG  = M/4;        // col-groups (threads across M)
    constexpr int NG  = BLK/CG;     // node-groups
    constexpr int NPT = TN/NG;      // nodes per thread
    constexpr int H   = M/F;        // heads
    constexpr int RW  = F/4;        // shuffle-reduce width per head
    __shared__ float xs[TN*K];
    const int nb = blockIdx.x;
    const int t  = threadIdx.x;
    const int nbase0 = nb*TN;
    if (nbase0 + TN <= NN){
        const float4* Xv = (const float4*)(X + (size_t)nbase0*K);
        float4* xv = (float4*)xs;
        #pragma unroll 4
        for (int i = t; i < TN*K/4; i += BLK) xv[i] = Xv[i];
    } else {
        for (int i = t; i < TN*K; i += BLK){
            size_t g = (size_t)nbase0*K + i;
            xs[i] = (g < (size_t)NN*K) ? X[g] : 0.f;
        }
    }
    __syncthreads();
    const int cg  = t % CG;
    const int ng  = t / CG;
    const int m4  = cg*4;
    const int nb0 = ng*NPT;
    float acc[NPT][4];
    #pragma unroll
    for (int j = 0; j < NPT; ++j){ acc[j][0]=0.f; acc[j][1]=0.f; acc[j][2]=0.f; acc[j][3]=0.f; }
    for (int k = 0; k < K; ++k){
        float4 wv = *(const float4*)(Wm + (size_t)k*M + m4);
        #pragma unroll
        for (int j = 0; j < NPT; ++j){
            float xv = xs[(nb0+j)*K + k];
            acc[j][0] += xv*wv.x; acc[j][1] += xv*wv.y;
            acc[j][2] += xv*wv.z; acc[j][3] += xv*wv.w;
        }
    }
    const float a0 = asrc[m4], a1 = asrc[m4+1], a2 = asrc[m4+2], a3 = asrc[m4+3];
    const float d0 = adst[m4], d1 = adst[m4+1], d2 = adst[m4+2], d3 = adst[m4+3];
    #pragma unroll
    for (int j = 0; j < NPT; ++j){
        int n = nbase0 + nb0 + j;
        bool ok = (n < NN);
        if (ok){
            float4 hv = make_float4(acc[j][0], acc[j][1], acc[j][2], acc[j][3]);
            *(float4*)(Hout + (size_t)n*M + m4) = hv;
        }
        float p1 = acc[j][0]*a0 + acc[j][1]*a1 + acc[j][2]*a2 + acc[j][3]*a3;
        float p2 = acc[j][0]*d0 + acc[j][1]*d1 + acc[j][2]*d2 + acc[j][3]*d3;
        #pragma unroll
        for (int o = RW/2; o > 0; o >>= 1){
            p1 += __shfl_down(p1, o, RW);
            p2 += __shfl_down(p2, o, RW);
        }
        if ((cg % RW) == 0 && ok){
            int h = cg / RW;
            AS[(size_t)n*H + h] = p1;
            AD[(size_t)n*H + h] = p2;
        }
    }
}

// ---------------- atomic-free GAT aggregation ----------------
// One block (M threads) per dst node; CSR walk + self loop. Softmax without
// max-subtraction (scores O(+-10); alpha mathematically identical). PReLU fused.
template<int M, int F>
__global__ __launch_bounds__(M) void gat_aggregate(
        const int* __restrict__ row, const int* __restrict__ adj,
        const float* __restrict__ Hfeat,
        const float* __restrict__ AS, const float* __restrict__ AD,
        const float* __restrict__ b, const float* __restrict__ p,
        float* __restrict__ Xout){
    constexpr int NH = M/F;
    const int d = blockIdx.x;
    const int m = threadIdx.x;
    const int h = m / F;
    const float ad = AD[(size_t)d*NH + h];
    float acc = 0.f, den = 0.f;
    {   // self loop
        float e = AS[(size_t)d*NH + h] + ad;
        e = (e >= 0.f) ? e : SLOPE*e;
        float wgt = expf(e);
        acc += Hfeat[(size_t)d*M + m] * wgt;
        den += wgt;
    }
    const int beg = row[d], end = row[d+1];
    for (int j = beg; j < end; ++j){
        int s = adj[j];
        float e = AS[(size_t)s*NH + h] + ad;
        e = (e >= 0.f) ? e : SLOPE*e;
        float wgt = expf(e);
        acc += Hfeat[(size_t)s*M + m] * wgt;
        den += wgt;
    }
    float v = acc/(den + 1e-16f) + b[m];
    float pw = p[m];
    Xout[(size_t)d*M + m] = (v >= 0.f) ? v : pw*v;
}

// column sums of x2 [NN,64] -> out[64]
__global__ void colsum(const float* __restrict__ X, float* __restrict__ out){
    __shared__ float red[256];
    const int c = blockIdx.x, t = threadIdx.x;
    float s = 0.f;
    for (int r = t; r < NN; r += 256) s += X[(size_t)r*64 + c];
    red[t] = s; __syncthreads();
    for (int o = 128; o > 0; o >>= 1){ if (t < o) red[t] += red[t+o]; __syncthreads(); }
    if (t == 0) out[c] = red[0];
}

// single block, 64 threads: summary vectors, bilinear Wc's, adv row-sums
__global__ void summary(const float* __restrict__ csum_o, const float* __restrict__ csum_a,
                        const float* __restrict__ mlpW, const float* __restrict__ mlpb,
                        const float* __restrict__ discW,
                        const float* __restrict__ advW, const float* __restrict__ advb,
                        float* __restrict__ Wc_o, float* __restrict__ Wc_a,
                        float* __restrict__ advRow, float* __restrict__ advbsum){
    __shared__ float s_o[64], s_a[64], h_o[64], h_a[64];
    const int t = threadIdx.x;
    s_o[t] = 1.f/(1.f + expf(-csum_o[t]/(float)NN));
    s_a[t] = 1.f/(1.f + expf(-csum_a[t]/(float)NN));
    __syncthreads();
    float ao = 0.f, aa = 0.f;
    for (int k = 0; k < 64; ++k){ float w = mlpW[k*64 + t]; ao += s_o[k]*w; aa += s_a[k]*w; }
    float bb = mlpb[t];
    h_o[t] = ao + bb; h_a[t] = aa + bb;
    __syncthreads();
    float wo = 0.f, wa = 0.f;
    for (int j = 0; j < 64; ++j){ float w = discW[t*64 + j]; wo += w*h_o[j]; wa += w*h_a[j]; }
    Wc_o[t] = wo; Wc_a[t] = wa;
    float ar = 0.f;
    for (int j = 0; j < 64; ++j) ar += advW[t*64 + j];
    advRow[t] = ar;
    float ab = advb[t];
    for (int o = 32; o > 0; o >>= 1) ab += __shfl_down(ab, o, 64);
    if (t == 0) advbsum[0] = ab;
}

// one wave (64 lanes) per node: 6 dot products + fp32 store of x2_o
__global__ void node_outputs(const float* __restrict__ x2o, const float* __restrict__ x2a,
                             const float* __restrict__ Wc_o, const float* __restrict__ Wc_a,
                             const float* __restrict__ advRow, const float* __restrict__ advbsum,
                             const float* __restrict__ discb,
                             float* __restrict__ out){
    const int n = blockIdx.x*4 + (threadIdx.x >> 6);
    const int l = threadIdx.x & 63;
    float xo = x2o[(size_t)n*64 + l], xa = x2a[(size_t)n*64 + l];
    float wo = Wc_o[l], wa = Wc_a[l], ar = advRow[l];
    float d1 = xo*wo, d2 = xa*wo, d3 = xa*wa, d4 = xo*wa, d5 = xo*ar, d6 = xa*ar;
    for (int o = 32; o > 0; o >>= 1){
        d1 += __shfl_down(d1, o, 64); d2 += __shfl_down(d2, o, 64);
        d3 += __shfl_down(d3, o, 64); d4 += __shfl_down(d4, o, 64);
        d5 += __shfl_down(d5, o, 64); d6 += __shfl_down(d6, o, 64);
    }
    out[O_X2 + (size_t)n*64 + l] = xo;
    if (l == 0){
        float db = discb[0];
        float ab = advbsum[0];
        out[O_RETOS  + n*2 + 0] = d1 + db;
        out[O_RETOS  + n*2 + 1] = d2 + db;
        out[O_RETOSA + n*2 + 0] = d3 + db;
        out[O_RETOSA + n*2 + 1] = d4 + db;
        out[O_LOGITS + n]       = d5 + ab;
        out[O_LOGITS + NN + n]  = d6 + ab;
    }
}

// fh = relu([x2[i0], x2[i1]] @ fW1 + fb1) : block per pair, 256 threads
__global__ void decoder1(const float* __restrict__ x2o, const int* __restrict__ idxArr,
                         const float* __restrict__ fW1, const float* __restrict__ fb1,
                         float* __restrict__ fh){
    __shared__ float e[128];
    const int b = blockIdx.x, t = threadIdx.x;
    const int i0 = idxArr[b], i1 = idxArr[BP + b];
    if (t < 64)        e[t] = x2o[(size_t)i0*64 + t];
    else if (t < 128)  e[t] = x2o[(size_t)i1*64 + (t - 64)];
    __syncthreads();
    for (int mm = t; mm < DEC; mm += 256){
        float acc = 0.f;
        #pragma unroll 8
        for (int k = 0; k < 128; ++k) acc += e[k] * fW1[(size_t)k*DEC + mm];
        acc += fb1[mm];
        fh[(size_t)b*DEC + mm] = (acc > 0.f) ? acc : 0.f;
    }
}

// log / log1 heads: one wave per pair
__global__ void decoder2(const float* __restrict__ fh,
                         const float* __restrict__ fW2, const float* __restrict__ fb2,
                         const float* __restrict__ fW3, const float* __restrict__ fb3,
                         float* __restrict__ out){
    const int b = blockIdx.x, t = threadIdx.x;
    float a0 = 0.f, a1 = 0.f, c0 = 0.f, c1 = 0.f;
    for (int m = t; m < DEC; m += 64){
        float v = fh[(size_t)b*DEC + m];
        a0 += v*fW2[m*2 + 0]; a1 += v*fW2[m*2 + 1];
        c0 += v*fW3[m*2 + 0]; c1 += v*fW3[m*2 + 1];
    }
    for (int o = 32; o > 0; o >>= 1){
        a0 += __shfl_down(a0, o, 64); a1 += __shfl_down(a1, o, 64);
        c0 += __shfl_down(c0, o, 64); c1 += __shfl_down(c1, o, 64);
    }
    if (t == 0){
        out[O_LOG  + b*2 + 0] = a0 + fb2[0];
        out[O_LOG  + b*2 + 1] = a1 + fb2[1];
        out[O_LOG1 + b*2 + 0] = c0 + fb3[0];
        out[O_LOG1 + b*2 + 1] = c1 + fb3[1];
    }
}

extern "C" void kernel_launch(void* const* d_in, const int* in_sizes, int n_in,
                              void* d_out, int out_size, void* d_ws, size_t ws_size,
                              hipStream_t stream){
    const float* x_o    = (const float*)d_in[0];
    const float* x_a    = (const float*)d_in[1];
    const int*   edge   = (const int*)d_in[2];
    const int*   idxp   = (const int*)d_in[3];
    const float* W1     = (const float*)d_in[4];
    const float* a_src1 = (const float*)d_in[5];
    const float* a_dst1 = (const float*)d_in[6];
    const float* b1     = (const float*)d_in[7];
    const float* p1     = (const float*)d_in[8];
    const float* W2     = (const float*)d_in[9];
    const float* a_src2 = (const float*)d_in[10];
    const float* a_dst2 = (const float*)d_in[11];
    const float* b2     = (const float*)d_in[12];
    const float* p2     = (const float*)d_in[13];
    const float* mlpW   = (const float*)d_in[14];
    const float* mlpb   = (const float*)d_in[15];
    const float* discW  = (const float*)d_in[16];
    const float* discb  = (const float*)d_in[17];
    const float* advW   = (const float*)d_in[18];
    const float* advb   = (const float*)d_in[19];
    const float* fW1    = (const float*)d_in[20];
    const float* fb1    = (const float*)d_in[21];
    const float* fW2    = (const float*)d_in[22];
    const float* fb2    = (const float*)d_in[23];
    const float* fW3    = (const float*)d_in[24];
    const float* fb3    = (const float*)d_in[25];

    const int* esrc = edge;
    const int* edst = edge + EE;

    // workspace carve-up (fp32), ~80 MB total
    float* w = (float*)d_ws;
    size_t off = 0;
    auto alloc = [&](size_t nfloats){ float* p = w + off; off += nfloats; return p; };
    float* hbuf  = alloc((size_t)NN * M1);   // H = X@W
    float* x1b   = alloc((size_t)NN * M1);   // layer-1 output; fh aliases after encoders
    float* asb   = alloc((size_t)NN * H1N);
    float* adb   = alloc((size_t)NN * H1N);
    float* x2o   = alloc((size_t)NN * M2);
    float* x2a   = alloc((size_t)NN * M2);
    int*   cnt   = (int*)alloc(NN);
    int*   row   = (int*)alloc(NN + 1);
    int*   cursor= (int*)alloc(NN);
    int*   adj   = (int*)alloc(EE);
    int*   bsum  = (int*)alloc(SCAN_NB + 1);
    float* smallb= alloc(512);
    float* fh     = x1b;                   // decoder scratch after encoders done
    float* csum_o = smallb;       float* csum_a = smallb + 64;
    float* Wc_o   = smallb + 128; float* Wc_a   = smallb + 192;
    float* advRow = smallb + 256; float* advbs  = smallb + 320;

    float* out = (float*)d_out;

    // ---- CSR build (once; reused by all 4 aggregations) ----
    hipMemsetAsync(cnt, 0, NN*sizeof(int), stream);
    hist_dst<<<(EE + 255)/256, 256, 0, stream>>>(edst, cnt);
    scan_blk<<<SCAN_NB, 1024, 0, stream>>>(cnt, row, bsum);
    scan_bsum<<<1, 64, 0, stream>>>(bsum, SCAN_NB);
    scan_fix<<<(NN + 255)/256, 256, 0, stream>>>(row, bsum, cursor);
    fill_csr<<<(EE + 255)/256, 256, 0, stream>>>(esrc, edst, cursor, adj);

    constexpr int TN = 32;
    const int gnodes = (NN + TN - 1) / TN;

    auto run_encoder = [&](const float* xin, float* x2out){
        // ---- layer 1: D=256 -> 4 heads x 32 ----
        gemm_attn_t<DIN, M1, F1, TN, 256><<<gnodes, 256, 0, stream>>>(
            xin, W1, a_src1, a_dst1, hbuf, asb, adb);
        gat_aggregate<M1, F1><<<NN, M1, 0, stream>>>(
            row, adj, hbuf, asb, adb, b1, p1, x1b);

        // ---- layer 2: 128 -> 64, 1 head ----
        gemm_attn_t<M1, M2, M2, TN, 256><<<gnodes, 256, 0, stream>>>(
            x1b, W2, a_src2, a_dst2, hbuf, asb, adb);
        gat_aggregate<M2, M2><<<NN, M2, 0, stream>>>(
            row, adj, hbuf, asb, adb, b2, p2, x2out);
    };

    run_encoder(x_o, x2o);
    run_encoder(x_a, x2a);

    colsum<<<64, 256, 0, stream>>>(x2o, csum_o);
    colsum<<<64, 256, 0, stream>>>(x2a, csum_a);
    summary<<<1, 64, 0, stream>>>(csum_o, csum_a, mlpW, mlpb, discW, advW, advb,
                                  Wc_o, Wc_a, advRow, advbs);
    node_outputs<<<NN/4, 256, 0, stream>>>(x2o, x2a, Wc_o, Wc_a, advRow, advbs, discb, out);
    decoder1<<<BP, 256, 0, stream>>>(x2o, idxp, fW1, fb1, fh);
    decoder2<<<BP, 64, 0, stream>>>(fh, fW2, fb2, fW3, fb3, out);
}

// Round 8
// 784.805 us; speedup vs baseline: 3.8515x; 1.0359x over previous
//
#include <hip/hip_runtime.h>
#include <hip/hip_bf16.h>
#include <math.h>

// ---------------- problem constants ----------------
constexpr int NN   = 50000;        // nodes
constexpr int EE   = 400000;       // edges (before self loops)
constexpr int EP   = EE + NN;      // edges + self loops
constexpr int DIN  = 256;          // input dim
constexpr int M1   = 128;          // heads*H1
constexpr int F1   = 32;           // per-head dim layer 1
constexpr int H1N  = 4;            // heads layer 1
constexpr int M2   = 64;           // H2
constexpr int BP   = 4096;         // entity pairs
constexpr int DEC  = 512;          // decoder hidden
constexpr float SLOPE = 0.2f;

// output layout (flat, fp32)
constexpr int O_LOG    = 0;                      // [BP,2]
constexpr int O_RETOS  = 8192;                   // [NN,2]
constexpr int O_RETOSA = 108192;                 // [NN,2]
constexpr int O_X2     = 208192;                 // [NN,64]
constexpr int O_LOGITS = 3408192;                // [1,2NN]
constexpr int O_LOG1   = 3508192;                // [BP,2]

constexpr int SCAN_NB = (NN + 1023) / 1024;      // 49 scan blocks

// ---------------- CSR build (by destination), done once per launch ----------------
__global__ void hist_dst(const int* __restrict__ edst, int* __restrict__ cnt){
    int i = blockIdx.x*blockDim.x + threadIdx.x;
    if (i < EE) atomicAdd(&cnt[edst[i]], 1);
}

__global__ __launch_bounds__(1024) void scan_blk(const int* __restrict__ cnt,
                                                 int* __restrict__ rowex,
                                                 int* __restrict__ bsum){
    __shared__ int wsum[16];
    const int t = threadIdx.x;
    const int idx = blockIdx.x*1024 + t;
    const int lane = t & 63, wid = t >> 6;
    int v = (idx < NN) ? cnt[idx] : 0;
    int s = v;
    #pragma unroll
    for (int o = 1; o < 64; o <<= 1){
        int u = __shfl_up(s, o, 64);
        if (lane >= o) s += u;
    }
    if (lane == 63) wsum[wid] = s;
    __syncthreads();
    if (wid == 0){
        int ws = (lane < 16) ? wsum[lane] : 0;
        #pragma unroll
        for (int o = 1; o < 16; o <<= 1){
            int u = __shfl_up(ws, o, 64);
            if (lane >= o) ws += u;
        }
        if (lane < 16) wsum[lane] = ws;
    }
    __syncthreads();
    int base = (wid > 0) ? wsum[wid-1] : 0;
    int incl = base + s;
    if (idx < NN) rowex[idx] = incl - v;
    if (t == 1023) bsum[blockIdx.x] = incl;
}

__global__ void scan_bsum(int* __restrict__ bsum, int nb){
    const int lane = threadIdx.x;
    int v = (lane < nb) ? bsum[lane] : 0;
    int s = v;
    #pragma unroll
    for (int o = 1; o < 64; o <<= 1){
        int u = __shfl_up(s, o, 64);
        if (lane >= o) s += u;
    }
    if (lane < nb) bsum[lane] = s - v;
}

__global__ void scan_fix(int* __restrict__ row, const int* __restrict__ bsum,
                         int* __restrict__ cursor){
    int idx = blockIdx.x*blockDim.x + threadIdx.x;
    if (idx < NN){
        int r = row[idx] + bsum[idx >> 10];
        row[idx] = r;
        cursor[idx] = r;
    }
    if (idx == 0) row[NN] = EE;
}

__global__ void fill_csr(const int* __restrict__ esrc, const int* __restrict__ edst,
                         int* __restrict__ cursor, int* __restrict__ adj){
    int i = blockIdx.x*blockDim.x + threadIdx.x;
    if (i >= EE) return;
    int d = edst[i];
    int slot = atomicAdd(&cursor[d], 1);
    adj[slot] = esrc[i];
}

// ---------------- K-tiled, double-buffered GEMM + attention-score fusion ------
// X tile staged in LDS per KT-column slab (double buffer, register prefetch).
// Per k: 1 W float4 (L1/L2) + NPT LDS broadcasts + 4*NPT FMAs.
template<int K, int M, int F, int TN, int BLK, int KT>
__global__ __launch_bounds__(BLK) void gemm_attn_t(
        const float* __restrict__ X, const float* __restrict__ Wm,
        const float* __restrict__ asrc, const float* __restrict__ adst,
        float* __restrict__ Hout, float* __restrict__ AS, float* __restrict__ AD){
    constexpr int CG  = M/4;        // col-groups (threads across M)
    constexpr int NG  = BLK/CG;     // node-groups
    constexpr int NPT = TN/NG;      // nodes per thread
    constexpr int H   = M/F;        // heads
    constexpr int RW  = F/4;        // shuffle-reduce width per head
    constexpr int NT  = K/KT;       // k-tiles
    constexpr int LV  = TN*KT/4;    // float4s per tile
    constexpr int PT  = LV/BLK;     // staged float4s per thread
    static_assert(LV % BLK == 0, "tile/block mismatch");
    __shared__ float4 xs[2][LV];
    const int nb = blockIdx.x;
    const int t  = threadIdx.x;
    const int nbase0 = nb*TN;
    const bool full = (nbase0 + TN <= NN);

    float4 pre[PT];
    auto load_tile = [&](int kt0){
        #pragma unroll
        for (int i = 0; i < PT; ++i){
            int id = t + i*BLK;
            int r  = id / (KT/4), c = id % (KT/4);
            int n  = nbase0 + r;
            float4 v = make_float4(0.f, 0.f, 0.f, 0.f);
            if (full || n < NN) v = *(const float4*)(X + (size_t)n*K + kt0 + c*4);
            pre[i] = v;
        }
    };
    auto store_tile = [&](int buf){
        #pragma unroll
        for (int i = 0; i < PT; ++i) xs[buf][t + i*BLK] = pre[i];
    };

    load_tile(0);
    store_tile(0);
    __syncthreads();

    const int cg  = t % CG;
    const int ng  = t / CG;
    const int m4  = cg*4;
    const int nb0 = ng*NPT;
    float acc[NPT][4];
    #pragma unroll
    for (int j = 0; j < NPT; ++j){ acc[j][0]=0.f; acc[j][1]=0.f; acc[j][2]=0.f; acc[j][3]=0.f; }

    int cur = 0;
    for (int tt = 0; tt < NT; ++tt){
        if (tt+1 < NT) load_tile((tt+1)*KT);
        const float* xsf = (const float*)xs[cur];
        #pragma unroll 2
        for (int k = 0; k < KT; ++k){
            float4 wv = *(const float4*)(Wm + (size_t)(tt*KT + k)*M + m4);
            #pragma unroll
            for (int j = 0; j < NPT; ++j){
                float xv = xsf[(nb0+j)*KT + k];
                acc[j][0] += xv*wv.x; acc[j][1] += xv*wv.y;
                acc[j][2] += xv*wv.z; acc[j][3] += xv*wv.w;
            }
        }
        if (tt+1 < NT){
            __syncthreads();
            store_tile(1-cur);
            __syncthreads();
            cur ^= 1;
        }
    }

    const float a0 = asrc[m4], a1 = asrc[m4+1], a2 = asrc[m4+2], a3 = asrc[m4+3];
    const float d0 = adst[m4], d1 = adst[m4+1], d2 = adst[m4+2], d3 = adst[m4+3];
    #pragma unroll
    for (int j = 0; j < NPT; ++j){
        int n = nbase0 + nb0 + j;
        bool ok = (n < NN);
        if (ok){
            float4 hv = make_float4(acc[j][0], acc[j][1], acc[j][2], acc[j][3]);
            *(float4*)(Hout + (size_t)n*M + m4) = hv;
        }
        float p1 = acc[j][0]*a0 + acc[j][1]*a1 + acc[j][2]*a2 + acc[j][3]*a3;
        float p2 = acc[j][0]*d0 + acc[j][1]*d1 + acc[j][2]*d2 + acc[j][3]*d3;
        #pragma unroll
        for (int o = RW/2; o > 0; o >>= 1){
            p1 += __shfl_down(p1, o, RW);
            p2 += __shfl_down(p2, o, RW);
        }
        if ((cg % RW) == 0 && ok){
            int h = cg / RW;
            AS[(size_t)n*H + h] = p1;
            AD[(size_t)n*H + h] = p2;
        }
    }
}

// ---------------- atomic-free GAT aggregation ----------------
template<int M, int F>
__global__ __launch_bounds__(M) void gat_aggregate(
        const int* __restrict__ row, const int* __restrict__ adj,
        const float* __restrict__ Hfeat,
        const float* __restrict__ AS, const float* __restrict__ AD,
        const float* __restrict__ b, const float* __restrict__ p,
        float* __restrict__ Xout){
    constexpr int NH = M/F;
    const int d = blockIdx.x;
    const int m = threadIdx.x;
    const int h = m / F;
    const float ad = AD[(size_t)d*NH + h];
    float acc = 0.f, den = 0.f;
    {   // self loop
        float e = AS[(size_t)d*NH + h] + ad;
        e = (e >= 0.f) ? e : SLOPE*e;
        float wgt = expf(e);
        acc += Hfeat[(size_t)d*M + m] * wgt;
        den += wgt;
    }
    const int beg = row[d], end = row[d+1];
    for (int j = beg; j < end; ++j){
        int s = adj[j];
        float e = AS[(size_t)s*NH + h] + ad;
        e = (e >= 0.f) ? e : SLOPE*e;
        float wgt = expf(e);
        acc += Hfeat[(size_t)s*M + m] * wgt;
        den += wgt;
    }
    float v = acc/(den + 1e-16f) + b[m];
    float pw = p[m];
    Xout[(size_t)d*M + m] = (v >= 0.f) ? v : pw*v;
}

// column sums of x2 [NN,64] -> out[64]
__global__ void colsum(const float* __restrict__ X, float* __restrict__ out){
    __shared__ float red[256];
    const int c = blockIdx.x, t = threadIdx.x;
    float s = 0.f;
    for (int r = t; r < NN; r += 256) s += X[(size_t)r*64 + c];
    red[t] = s; __syncthreads();
    for (int o = 128; o > 0; o >>= 1){ if (t < o) red[t] += red[t+o]; __syncthreads(); }
    if (t == 0) out[c] = red[0];
}

// single block, 64 threads: summary vectors, bilinear Wc's, adv row-sums
__global__ void summary(const float* __restrict__ csum_o, const float* __restrict__ csum_a,
                        const float* __restrict__ mlpW, const float* __restrict__ mlpb,
                        const float* __restrict__ discW,
                        const float* __restrict__ advW, const float* __restrict__ advb,
                        float* __restrict__ Wc_o, float* __restrict__ Wc_a,
                        float* __restrict__ advRow, float* __restrict__ advbsum){
    __shared__ float s_o[64], s_a[64], h_o[64], h_a[64];
    const int t = threadIdx.x;
    s_o[t] = 1.f/(1.f + expf(-csum_o[t]/(float)NN));
    s_a[t] = 1.f/(1.f + expf(-csum_a[t]/(float)NN));
    __syncthreads();
    float ao = 0.f, aa = 0.f;
    for (int k = 0; k < 64; ++k){ float w = mlpW[k*64 + t]; ao += s_o[k]*w; aa += s_a[k]*w; }
    float bb = mlpb[t];
    h_o[t] = ao + bb; h_a[t] = aa + bb;
    __syncthreads();
    float wo = 0.f, wa = 0.f;
    for (int j = 0; j < 64; ++j){ float w = discW[t*64 + j]; wo += w*h_o[j]; wa += w*h_a[j]; }
    Wc_o[t] = wo; Wc_a[t] = wa;
    float ar = 0.f;
    for (int j = 0; j < 64; ++j) ar += advW[t*64 + j];
    advRow[t] = ar;
    float ab = advb[t];
    for (int o = 32; o > 0; o >>= 1) ab += __shfl_down(ab, o, 64);
    if (t == 0) advbsum[0] = ab;
}

// one wave (64 lanes) per node: 6 dot products + fp32 store of x2_o
__global__ void node_outputs(const float* __restrict__ x2o, const float* __restrict__ x2a,
                             const float* __restrict__ Wc_o, const float* __restrict__ Wc_a,
                             const float* __restrict__ advRow, const float* __restrict__ advbsum,
                             const float* __restrict__ discb,
                             float* __restrict__ out){
    const int n = blockIdx.x*4 + (threadIdx.x >> 6);
    const int l = threadIdx.x & 63;
    float xo = x2o[(size_t)n*64 + l], xa = x2a[(size_t)n*64 + l];
    float wo = Wc_o[l], wa = Wc_a[l], ar = advRow[l];
    float d1 = xo*wo, d2 = xa*wo, d3 = xa*wa, d4 = xo*wa, d5 = xo*ar, d6 = xa*ar;
    for (int o = 32; o > 0; o >>= 1){
        d1 += __shfl_down(d1, o, 64); d2 += __shfl_down(d2, o, 64);
        d3 += __shfl_down(d3, o, 64); d4 += __shfl_down(d4, o, 64);
        d5 += __shfl_down(d5, o, 64); d6 += __shfl_down(d6, o, 64);
    }
    out[O_X2 + (size_t)n*64 + l] = xo;
    if (l == 0){
        float db = discb[0];
        float ab = advbsum[0];
        out[O_RETOS  + n*2 + 0] = d1 + db;
        out[O_RETOS  + n*2 + 1] = d2 + db;
        out[O_RETOSA + n*2 + 0] = d3 + db;
        out[O_RETOSA + n*2 + 1] = d4 + db;
        out[O_LOGITS + n]       = d5 + ab;
        out[O_LOGITS + NN + n]  = d6 + ab;
    }
}

// fh = relu([x2[i0], x2[i1]] @ fW1 + fb1) : block per pair, 256 threads
__global__ void decoder1(const float* __restrict__ x2o, const int* __restrict__ idxArr,
                         const float* __restrict__ fW1, const float* __restrict__ fb1,
                         float* __restrict__ fh){
    __shared__ float e[128];
    const int b = blockIdx.x, t = threadIdx.x;
    const int i0 = idxArr[b], i1 = idxArr[BP + b];
    if (t < 64)        e[t] = x2o[(size_t)i0*64 + t];
    else if (t < 128)  e[t] = x2o[(size_t)i1*64 + (t - 64)];
    __syncthreads();
    for (int mm = t; mm < DEC; mm += 256){
        float acc = 0.f;
        #pragma unroll 8
        for (int k = 0; k < 128; ++k) acc += e[k] * fW1[(size_t)k*DEC + mm];
        acc += fb1[mm];
        fh[(size_t)b*DEC + mm] = (acc > 0.f) ? acc : 0.f;
    }
}

// log / log1 heads: one wave per pair
__global__ void decoder2(const float* __restrict__ fh,
                         const float* __restrict__ fW2, const float* __restrict__ fb2,
                         const float* __restrict__ fW3, const float* __restrict__ fb3,
                         float* __restrict__ out){
    const int b = blockIdx.x, t = threadIdx.x;
    float a0 = 0.f, a1 = 0.f, c0 = 0.f, c1 = 0.f;
    for (int m = t; m < DEC; m += 64){
        float v = fh[(size_t)b*DEC + m];
        a0 += v*fW2[m*2 + 0]; a1 += v*fW2[m*2 + 1];
        c0 += v*fW3[m*2 + 0]; c1 += v*fW3[m*2 + 1];
    }
    for (int o = 32; o > 0; o >>= 1){
        a0 += __shfl_down(a0, o, 64); a1 += __shfl_down(a1, o, 64);
        c0 += __shfl_down(c0, o, 64); c1 += __shfl_down(c1, o, 64);
    }
    if (t == 0){
        out[O_LOG  + b*2 + 0] = a0 + fb2[0];
        out[O_LOG  + b*2 + 1] = a1 + fb2[1];
        out[O_LOG1 + b*2 + 0] = c0 + fb3[0];
        out[O_LOG1 + b*2 + 1] = c1 + fb3[1];
    }
}

extern "C" void kernel_launch(void* const* d_in, const int* in_sizes, int n_in,
                              void* d_out, int out_size, void* d_ws, size_t ws_size,
                              hipStream_t stream){
    const float* x_o    = (const float*)d_in[0];
    const float* x_a    = (const float*)d_in[1];
    const int*   edge   = (const int*)d_in[2];
    const int*   idxp   = (const int*)d_in[3];
    const float* W1     = (const float*)d_in[4];
    const float* a_src1 = (const float*)d_in[5];
    const float* a_dst1 = (const float*)d_in[6];
    const float* b1     = (const float*)d_in[7];
    const float* p1     = (const float*)d_in[8];
    const float* W2     = (const float*)d_in[9];
    const float* a_src2 = (const float*)d_in[10];
    const float* a_dst2 = (const float*)d_in[11];
    const float* b2     = (const float*)d_in[12];
    const float* p2     = (const float*)d_in[13];
    const float* mlpW   = (const float*)d_in[14];
    const float* mlpb   = (const float*)d_in[15];
    const float* discW  = (const float*)d_in[16];
    const float* discb  = (const float*)d_in[17];
    const float* advW   = (const float*)d_in[18];
    const float* advb   = (const float*)d_in[19];
    const float* fW1    = (const float*)d_in[20];
    const float* fb1    = (const float*)d_in[21];
    const float* fW2    = (const float*)d_in[22];
    const float* fb2    = (const float*)d_in[23];
    const float* fW3    = (const float*)d_in[24];
    const float* fb3    = (const float*)d_in[25];

    const int* esrc = edge;
    const int* edst = edge + EE;

    // workspace carve-up (fp32), ~80 MB total
    float* w = (float*)d_ws;
    size_t off = 0;
    auto alloc = [&](size_t nfloats){ float* p = w + off; off += nfloats; return p; };
    float* hbuf  = alloc((size_t)NN * M1);   // H = X@W
    float* x1b   = alloc((size_t)NN * M1);   // layer-1 output; fh aliases after encoders
    float* asb   = alloc((size_t)NN * H1N);
    float* adb   = alloc((size_t)NN * H1N);
    float* x2o   = alloc((size_t)NN * M2);
    float* x2a   = alloc((size_t)NN * M2);
    int*   cnt   = (int*)alloc(NN);
    int*   row   = (int*)alloc(NN + 1);
    int*   cursor= (int*)alloc(NN);
    int*   adj   = (int*)alloc(EE);
    int*   bsum  = (int*)alloc(SCAN_NB + 1);
    float* smallb= alloc(512);
    float* fh     = x1b;                   // decoder scratch after encoders done
    float* csum_o = smallb;       float* csum_a = smallb + 64;
    float* Wc_o   = smallb + 128; float* Wc_a   = smallb + 192;
    float* advRow = smallb + 256; float* advbs  = smallb + 320;

    float* out = (float*)d_out;

    // ---- CSR build (once; reused by all 4 aggregations) ----
    hipMemsetAsync(cnt, 0, NN*sizeof(int), stream);
    hist_dst<<<(EE + 255)/256, 256, 0, stream>>>(edst, cnt);
    scan_blk<<<SCAN_NB, 1024, 0, stream>>>(cnt, row, bsum);
    scan_bsum<<<1, 64, 0, stream>>>(bsum, SCAN_NB);
    scan_fix<<<(NN + 255)/256, 256, 0, stream>>>(row, bsum, cursor);
    fill_csr<<<(EE + 255)/256, 256, 0, stream>>>(esrc, edst, cursor, adj);

    constexpr int TN1 = 32, TN2 = 64;
    const int g1 = (NN + TN1 - 1) / TN1;
    const int g2 = (NN + TN2 - 1) / TN2;

    auto run_encoder = [&](const float* xin, float* x2out){
        // ---- layer 1: D=256 -> 4 heads x 32 ----
        gemm_attn_t<DIN, M1, F1, TN1, 256, 64><<<g1, 256, 0, stream>>>(
            xin, W1, a_src1, a_dst1, hbuf, asb, adb);
        gat_aggregate<M1, F1><<<NN, M1, 0, stream>>>(
            row, adj, hbuf, asb, adb, b1, p1, x1b);

        // ---- layer 2: 128 -> 64, 1 head ----
        gemm_attn_t<M1, M2, M2, TN2, 256, 64><<<g2, 256, 0, stream>>>(
            x1b, W2, a_src2, a_dst2, hbuf, asb, adb);
        gat_aggregate<M2, M2><<<NN, M2, 0, stream>>>(
            row, adj, hbuf, asb, adb, b2, p2, x2out);
    };

    run_encoder(x_o, x2o);
    run_encoder(x_a, x2a);

    colsum<<<64, 256, 0, stream>>>(x2o, csum_o);
    colsum<<<64, 256, 0, stream>>>(x2a, csum_a);
    summary<<<1, 64, 0, stream>>>(csum_o, csum_a, mlpW, mlpb, discW, advW, advb,
                                  Wc_o, Wc_a, advRow, advbs);
    node_outputs<<<NN/4, 256, 0, stream>>>(x2o, x2a, Wc_o, Wc_a, advRow, advbs, discb, out);
    decoder1<<<BP, 256, 0, stream>>>(x2o, idxp, fW1, fb1, fh);
    decoder2<<<BP, 64, 0, stream>>>(fh, fW2, fb2, fW3, fb3, out);
}

// Round 9
// 720.048 us; speedup vs baseline: 4.1979x; 1.0899x over previous
//
#include <hip/hip_runtime.h>
#include <hip/hip_bf16.h>
#include <math.h>

// ---------------- problem constants ----------------
constexpr int NN   = 50000;        // nodes (= 3125 * 16, no MFMA tail)
constexpr int EE   = 400000;       // edges (before self loops)
constexpr int EP   = EE + NN;      // edges + self loops
constexpr int DIN  = 256;          // input dim
constexpr int M1   = 128;          // heads*H1
constexpr int F1   = 32;           // per-head dim layer 1
constexpr int H1N  = 4;            // heads layer 1
constexpr int M2   = 64;           // H2
constexpr int BP   = 4096;         // entity pairs
constexpr int DEC  = 512;          // decoder hidden
constexpr float SLOPE = 0.2f;

// output layout (flat, fp32)
constexpr int O_LOG    = 0;
constexpr int O_RETOS  = 8192;
constexpr int O_RETOSA = 108192;
constexpr int O_X2     = 208192;
constexpr int O_LOGITS = 3408192;
constexpr int O_LOG1   = 3508192;

constexpr int SCAN_NB = (NN + 1023) / 1024;

typedef __attribute__((ext_vector_type(8))) short short8;   // 8 bf16 = 4 VGPRs
typedef __attribute__((ext_vector_type(4))) float f32x4;

__device__ __forceinline__ short f2bs(float v){
    __hip_bfloat16 h = __float2bfloat16(v);
    unsigned short u; __builtin_memcpy(&u, &h, 2);
    return (short)u;
}

// ---------------- CSR build ----------------
__global__ void hist_dst(const int* __restrict__ edst, int* __restrict__ cnt){
    int i = blockIdx.x*blockDim.x + threadIdx.x;
    if (i < EE) atomicAdd(&cnt[edst[i]], 1);
}

__global__ __launch_bounds__(1024) void scan_blk(const int* __restrict__ cnt,
                                                 int* __restrict__ rowex,
                                                 int* __restrict__ bsum){
    __shared__ int wsum[16];
    const int t = threadIdx.x;
    const int idx = blockIdx.x*1024 + t;
    const int lane = t & 63, wid = t >> 6;
    int v = (idx < NN) ? cnt[idx] : 0;
    int s = v;
    #pragma unroll
    for (int o = 1; o < 64; o <<= 1){
        int u = __shfl_up(s, o, 64);
        if (lane >= o) s += u;
    }
    if (lane == 63) wsum[wid] = s;
    __syncthreads();
    if (wid == 0){
        int ws = (lane < 16) ? wsum[lane] : 0;
        #pragma unroll
        for (int o = 1; o < 16; o <<= 1){
            int u = __shfl_up(ws, o, 64);
            if (lane >= o) ws += u;
        }
        if (lane < 16) wsum[lane] = ws;
    }
    __syncthreads();
    int base = (wid > 0) ? wsum[wid-1] : 0;
    int incl = base + s;
    if (idx < NN) rowex[idx] = incl - v;
    if (t == 1023) bsum[blockIdx.x] = incl;
}

__global__ void scan_bsum(int* __restrict__ bsum, int nb){
    const int lane = threadIdx.x;
    int v = (lane < nb) ? bsum[lane] : 0;
    int s = v;
    #pragma unroll
    for (int o = 1; o < 64; o <<= 1){
        int u = __shfl_up(s, o, 64);
        if (lane >= o) s += u;
    }
    if (lane < nb) bsum[lane] = s - v;
}

__global__ void scan_fix(int* __restrict__ row, const int* __restrict__ bsum,
                         int* __restrict__ cursor){
    int idx = blockIdx.x*blockDim.x + threadIdx.x;
    if (idx < NN){
        int r = row[idx] + bsum[idx >> 10];
        row[idx] = r;
        cursor[idx] = r;
    }
    if (idx == 0) row[NN] = EE;
}

__global__ void fill_csr(const int* __restrict__ esrc, const int* __restrict__ edst,
                         int* __restrict__ cursor, int* __restrict__ adj){
    int i = blockIdx.x*blockDim.x + threadIdx.x;
    if (i >= EE) return;
    int d = edst[i];
    int slot = atomicAdd(&cursor[d], 1);
    adj[slot] = esrc[i];
}

// ---------------- W pack: fp32 [K][M] -> bf16 B-fragment layout ----------------
// B-frag lane holds B[k = quad*8+j][n = lane&15]; packed as
// Wpk[((kb*CT + ct)*64 + lane)*8 + j].
__global__ void pack_w(const float* __restrict__ W, __hip_bfloat16* __restrict__ Wpk,
                       int K, int M){
    int i = blockIdx.x*blockDim.x + threadIdx.x;
    if (i >= K*M) return;
    int k = i / M, c = i - k*M;
    int kb = k >> 5, r = k & 31, quad = r >> 3, j = r & 7;
    int ct = c >> 4, ln = quad*16 + (c & 15);
    int CT = M >> 4;
    size_t dst = (((size_t)kb*CT + ct)*64 + ln)*8 + j;
    Wpk[dst] = __float2bfloat16(W[i]);
}

// ---------------- MFMA GEMM: H = bf16(X @ W), one wave per 16-node tile ------
// A-frag: A[m=lane&15][k=quad*8+j]  (m89/m120 verified layout)
// C/D   : col=lane&15, row=quad*4+reg
template<int K, int M, bool AF32>
__global__ __launch_bounds__(256) void gemm_mfma(
        const void* __restrict__ Xv, const __hip_bfloat16* __restrict__ Wpk,
        __hip_bfloat16* __restrict__ Hb){
    constexpr int CT = M/16;
    constexpr int KB = K/32;
    const int wave = (blockIdx.x*256 + threadIdx.x) >> 6;
    const int lane = threadIdx.x & 63;
    const int n0 = wave*16;
    if (n0 >= NN) return;
    const int arow = lane & 15;
    const int quad = lane >> 4;

    f32x4 acc[CT];
    #pragma unroll
    for (int ct = 0; ct < CT; ++ct) acc[ct] = (f32x4){0.f,0.f,0.f,0.f};

    for (int kb = 0; kb < KB; ++kb){
        const int kbase = kb*32 + quad*8;
        short8 af;
        if constexpr (AF32){
            const float* ap = (const float*)Xv + (size_t)(n0 + arow)*K + kbase;
            float4 v0 = *(const float4*)ap;
            float4 v1 = *(const float4*)(ap + 4);
            af[0]=f2bs(v0.x); af[1]=f2bs(v0.y); af[2]=f2bs(v0.z); af[3]=f2bs(v0.w);
            af[4]=f2bs(v1.x); af[5]=f2bs(v1.y); af[6]=f2bs(v1.z); af[7]=f2bs(v1.w);
        } else {
            af = *(const short8*)((const __hip_bfloat16*)Xv + (size_t)(n0 + arow)*K + kbase);
        }
        const __hip_bfloat16* wp = Wpk + (size_t)kb*CT*64*8;
        #pragma unroll
        for (int ct = 0; ct < CT; ++ct){
            short8 bfr = *(const short8*)(wp + ((size_t)ct*64 + lane)*8);
            acc[ct] = __builtin_amdgcn_mfma_f32_16x16x32_bf16(af, bfr, acc[ct], 0, 0, 0);
        }
    }
    #pragma unroll
    for (int ct = 0; ct < CT; ++ct){
        #pragma unroll
        for (int r = 0; r < 4; ++r){
            int n = n0 + quad*4 + r;
            Hb[(size_t)n*M + ct*16 + arow] = __float2bfloat16(acc[ct][r]);
        }
    }
}

// ---------------- attention scores from bf16 H ----------------
template<int M, int F>
__global__ __launch_bounds__(M) void attn_scores(
        const __hip_bfloat16* __restrict__ Hb,
        const float* __restrict__ asrc, const float* __restrict__ adst,
        float* __restrict__ AS, float* __restrict__ AD){
    const int n = blockIdx.x, t = threadIdx.x;
    float h = __bfloat162float(Hb[(size_t)n*M + t]);
    float s1 = h*asrc[t], s2 = h*adst[t];
    #pragma unroll
    for (int o = F>>1; o > 0; o >>= 1){
        s1 += __shfl_down(s1, o, F);
        s2 += __shfl_down(s2, o, F);
    }
    if ((t & (F-1)) == 0){
        AS[(size_t)n*(M/F) + t/F] = s1;
        AD[(size_t)n*(M/F) + t/F] = s2;
    }
}

// ---------------- atomic-free GAT aggregation (bf16 H in) ----------------
// Softmax without max-subtraction (scores O(+-10); alpha mathematically identical).
template<int M, int F, bool OUTBF>
__global__ __launch_bounds__(M) void gat_aggregate(
        const int* __restrict__ row, const int* __restrict__ adj,
        const __hip_bfloat16* __restrict__ Hfeat,
        const float* __restrict__ AS, const float* __restrict__ AD,
        const float* __restrict__ b, const float* __restrict__ p,
        float* __restrict__ outF, __hip_bfloat16* __restrict__ outB){
    constexpr int NH = M/F;
    const int d = blockIdx.x;
    const int m = threadIdx.x;
    const int h = m / F;
    const float ad = AD[(size_t)d*NH + h];
    float acc = 0.f, den = 0.f;
    {   // self loop
        float e = AS[(size_t)d*NH + h] + ad;
        e = (e >= 0.f) ? e : SLOPE*e;
        float wgt = expf(e);
        acc += __bfloat162float(Hfeat[(size_t)d*M + m]) * wgt;
        den += wgt;
    }
    const int beg = row[d], end = row[d+1];
    for (int j = beg; j < end; ++j){
        int s = adj[j];
        float e = AS[(size_t)s*NH + h] + ad;
        e = (e >= 0.f) ? e : SLOPE*e;
        float wgt = expf(e);
        acc += __bfloat162float(Hfeat[(size_t)s*M + m]) * wgt;
        den += wgt;
    }
    float v = acc/(den + 1e-16f) + b[m];
    float pw = p[m];
    v = (v >= 0.f) ? v : pw*v;
    if constexpr (OUTBF) outB[(size_t)d*M + m] = __float2bfloat16(v);
    else                 outF[(size_t)d*M + m] = v;
}

// column sums of x2 [NN,64] -> out[64]
__global__ void colsum(const float* __restrict__ X, float* __restrict__ out){
    __shared__ float red[256];
    const int c = blockIdx.x, t = threadIdx.x;
    float s = 0.f;
    for (int r = t; r < NN; r += 256) s += X[(size_t)r*64 + c];
    red[t] = s; __syncthreads();
    for (int o = 128; o > 0; o >>= 1){ if (t < o) red[t] += red[t+o]; __syncthreads(); }
    if (t == 0) out[c] = red[0];
}

__global__ void summary(const float* __restrict__ csum_o, const float* __restrict__ csum_a,
                        const float* __restrict__ mlpW, const float* __restrict__ mlpb,
                        const float* __restrict__ discW,
                        const float* __restrict__ advW, const float* __restrict__ advb,
                        float* __restrict__ Wc_o, float* __restrict__ Wc_a,
                        float* __restrict__ advRow, float* __restrict__ advbsum){
    __shared__ float s_o[64], s_a[64], h_o[64], h_a[64];
    const int t = threadIdx.x;
    s_o[t] = 1.f/(1.f + expf(-csum_o[t]/(float)NN));
    s_a[t] = 1.f/(1.f + expf(-csum_a[t]/(float)NN));
    __syncthreads();
    float ao = 0.f, aa = 0.f;
    for (int k = 0; k < 64; ++k){ float w = mlpW[k*64 + t]; ao += s_o[k]*w; aa += s_a[k]*w; }
    float bb = mlpb[t];
    h_o[t] = ao + bb; h_a[t] = aa + bb;
    __syncthreads();
    float wo = 0.f, wa = 0.f;
    for (int j = 0; j < 64; ++j){ float w = discW[t*64 + j]; wo += w*h_o[j]; wa += w*h_a[j]; }
    Wc_o[t] = wo; Wc_a[t] = wa;
    float ar = 0.f;
    for (int j = 0; j < 64; ++j) ar += advW[t*64 + j];
    advRow[t] = ar;
    float ab = advb[t];
    for (int o = 32; o > 0; o >>= 1) ab += __shfl_down(ab, o, 64);
    if (t == 0) advbsum[0] = ab;
}

__global__ void node_outputs(const float* __restrict__ x2o, const float* __restrict__ x2a,
                             const float* __restrict__ Wc_o, const float* __restrict__ Wc_a,
                             const float* __restrict__ advRow, const float* __restrict__ advbsum,
                             const float* __restrict__ discb,
                             float* __restrict__ out){
    const int n = blockIdx.x*4 + (threadIdx.x >> 6);
    const int l = threadIdx.x & 63;
    float xo = x2o[(size_t)n*64 + l], xa = x2a[(size_t)n*64 + l];
    float wo = Wc_o[l], wa = Wc_a[l], ar = advRow[l];
    float d1 = xo*wo, d2 = xa*wo, d3 = xa*wa, d4 = xo*wa, d5 = xo*ar, d6 = xa*ar;
    for (int o = 32; o > 0; o >>= 1){
        d1 += __shfl_down(d1, o, 64); d2 += __shfl_down(d2, o, 64);
        d3 += __shfl_down(d3, o, 64); d4 += __shfl_down(d4, o, 64);
        d5 += __shfl_down(d5, o, 64); d6 += __shfl_down(d6, o, 64);
    }
    out[O_X2 + (size_t)n*64 + l] = xo;
    if (l == 0){
        float db = discb[0];
        float ab = advbsum[0];
        out[O_RETOS  + n*2 + 0] = d1 + db;
        out[O_RETOS  + n*2 + 1] = d2 + db;
        out[O_RETOSA + n*2 + 0] = d3 + db;
        out[O_RETOSA + n*2 + 1] = d4 + db;
        out[O_LOGITS + n]       = d5 + ab;
        out[O_LOGITS + NN + n]  = d6 + ab;
    }
}

__global__ void decoder1(const float* __restrict__ x2o, const int* __restrict__ idxArr,
                         const float* __restrict__ fW1, const float* __restrict__ fb1,
                         float* __restrict__ fh){
    __shared__ float e[128];
    const int b = blockIdx.x, t = threadIdx.x;
    const int i0 = idxArr[b], i1 = idxArr[BP + b];
    if (t < 64)        e[t] = x2o[(size_t)i0*64 + t];
    else if (t < 128)  e[t] = x2o[(size_t)i1*64 + (t - 64)];
    __syncthreads();
    for (int mm = t; mm < DEC; mm += 256){
        float acc = 0.f;
        #pragma unroll 8
        for (int k = 0; k < 128; ++k) acc += e[k] * fW1[(size_t)k*DEC + mm];
        acc += fb1[mm];
        fh[(size_t)b*DEC + mm] = (acc > 0.f) ? acc : 0.f;
    }
}

__global__ void decoder2(const float* __restrict__ fh,
                         const float* __restrict__ fW2, const float* __restrict__ fb2,
                         const float* __restrict__ fW3, const float* __restrict__ fb3,
                         float* __restrict__ out){
    const int b = blockIdx.x, t = threadIdx.x;
    float a0 = 0.f, a1 = 0.f, c0 = 0.f, c1 = 0.f;
    for (int m = t; m < DEC; m += 64){
        float v = fh[(size_t)b*DEC + m];
        a0 += v*fW2[m*2 + 0]; a1 += v*fW2[m*2 + 1];
        c0 += v*fW3[m*2 + 0]; c1 += v*fW3[m*2 + 1];
    }
    for (int o = 32; o > 0; o >>= 1){
        a0 += __shfl_down(a0, o, 64); a1 += __shfl_down(a1, o, 64);
        c0 += __shfl_down(c0, o, 64); c1 += __shfl_down(c1, o, 64);
    }
    if (t == 0){
        out[O_LOG  + b*2 + 0] = a0 + fb2[0];
        out[O_LOG  + b*2 + 1] = a1 + fb2[1];
        out[O_LOG1 + b*2 + 0] = c0 + fb3[0];
        out[O_LOG1 + b*2 + 1] = c1 + fb3[1];
    }
}

extern "C" void kernel_launch(void* const* d_in, const int* in_sizes, int n_in,
                              void* d_out, int out_size, void* d_ws, size_t ws_size,
                              hipStream_t stream){
    const float* x_o    = (const float*)d_in[0];
    const float* x_a    = (const float*)d_in[1];
    const int*   edge   = (const int*)d_in[2];
    const int*   idxp   = (const int*)d_in[3];
    const float* W1     = (const float*)d_in[4];
    const float* a_src1 = (const float*)d_in[5];
    const float* a_dst1 = (const float*)d_in[6];
    const float* b1     = (const float*)d_in[7];
    const float* p1     = (const float*)d_in[8];
    const float* W2     = (const float*)d_in[9];
    const float* a_src2 = (const float*)d_in[10];
    const float* a_dst2 = (const float*)d_in[11];
    const float* b2     = (const float*)d_in[12];
    const float* p2     = (const float*)d_in[13];
    const float* mlpW   = (const float*)d_in[14];
    const float* mlpb   = (const float*)d_in[15];
    const float* discW  = (const float*)d_in[16];
    const float* discb  = (const float*)d_in[17];
    const float* advW   = (const float*)d_in[18];
    const float* advb   = (const float*)d_in[19];
    const float* fW1    = (const float*)d_in[20];
    const float* fb1    = (const float*)d_in[21];
    const float* fW2    = (const float*)d_in[22];
    const float* fb2    = (const float*)d_in[23];
    const float* fW3    = (const float*)d_in[24];
    const float* fb3    = (const float*)d_in[25];

    const int* esrc = edge;
    const int* edst = edge + EE;

    // workspace carve-up (fp32 units), ~60 MB total
    float* w = (float*)d_ws;
    size_t off = 0;
    auto alloc = [&](size_t nfloats){ float* p = w + off; off += nfloats; return p; };
    __hip_bfloat16* Hb   = (__hip_bfloat16*)alloc((size_t)NN*M1/2);  // H bf16; fh aliases later
    __hip_bfloat16* x1b  = (__hip_bfloat16*)alloc((size_t)NN*M1/2);  // layer-1 out, bf16
    float* asb   = alloc((size_t)NN*H1N);
    float* adb   = alloc((size_t)NN*H1N);
    float* x2o   = alloc((size_t)NN*M2);
    float* x2a   = alloc((size_t)NN*M2);
    __hip_bfloat16* Wpk1 = (__hip_bfloat16*)alloc((size_t)DIN*M1/2);
    __hip_bfloat16* Wpk2 = (__hip_bfloat16*)alloc((size_t)M1*M2/2);
    int*   cnt   = (int*)alloc(NN);
    int*   row   = (int*)alloc(NN + 1);
    int*   cursor= (int*)alloc(NN);
    int*   adj   = (int*)alloc(EE);
    int*   bsum  = (int*)alloc(SCAN_NB + 1);
    float* smallb= alloc(512);
    float* fh     = (float*)Hb;            // decoder scratch after encoders done
    float* csum_o = smallb;       float* csum_a = smallb + 64;
    float* Wc_o   = smallb + 128; float* Wc_a   = smallb + 192;
    float* advRow = smallb + 256; float* advbs  = smallb + 320;

    float* out = (float*)d_out;

    // ---- CSR build + W packing (once) ----
    hipMemsetAsync(cnt, 0, NN*sizeof(int), stream);
    hist_dst<<<(EE + 255)/256, 256, 0, stream>>>(edst, cnt);
    scan_blk<<<SCAN_NB, 1024, 0, stream>>>(cnt, row, bsum);
    scan_bsum<<<1, 64, 0, stream>>>(bsum, SCAN_NB);
    scan_fix<<<(NN + 255)/256, 256, 0, stream>>>(row, bsum, cursor);
    fill_csr<<<(EE + 255)/256, 256, 0, stream>>>(esrc, edst, cursor, adj);
    pack_w<<<(DIN*M1 + 255)/256, 256, 0, stream>>>(W1, Wpk1, DIN, M1);
    pack_w<<<(M1*M2 + 255)/256, 256, 0, stream>>>(W2, Wpk2, M1, M2);

    const int gw = ((NN/16) + 3) / 4;   // 3125 waves, 4 per block

    auto run_encoder = [&](const float* xin, float* x2out){
        // ---- layer 1: D=256 -> 4 heads x 32 ----
        gemm_mfma<DIN, M1, true><<<gw, 256, 0, stream>>>(xin, Wpk1, Hb);
        attn_scores<M1, F1><<<NN, M1, 0, stream>>>(Hb, a_src1, a_dst1, asb, adb);
        gat_aggregate<M1, F1, true><<<NN, M1, 0, stream>>>(
            row, adj, Hb, asb, adb, b1, p1, nullptr, x1b);

        // ---- layer 2: 128 -> 64, 1 head ----
        gemm_mfma<M1, M2, false><<<gw, 256, 0, stream>>>(x1b, Wpk2, Hb);
        attn_scores<M2, M2><<<NN, M2, 0, stream>>>(Hb, a_src2, a_dst2, asb, adb);
        gat_aggregate<M2, M2, false><<<NN, M2, 0, stream>>>(
            row, adj, Hb, asb, adb, b2, p2, x2out, nullptr);
    };

    run_encoder(x_o, x2o);
    run_encoder(x_a, x2a);

    colsum<<<64, 256, 0, stream>>>(x2o, csum_o);
    colsum<<<64, 256, 0, stream>>>(x2a, csum_a);
    summary<<<1, 64, 0, stream>>>(csum_o, csum_a, mlpW, mlpb, discW, advW, advb,
                                  Wc_o, Wc_a, advRow, advbs);
    node_outputs<<<NN/4, 256, 0, stream>>>(x2o, x2a, Wc_o, Wc_a, advRow, advbs, discb, out);
    decoder1<<<BP, 256, 0, stream>>>(x2o, idxp, fW1, fb1, fh);
    decoder2<<<BP, 64, 0, stream>>>(fh, fW2, fb2, fW3, fb3, out);
}

// Round 10
// 622.514 us; speedup vs baseline: 4.8556x; 1.1567x over previous
//
#include <hip/hip_runtime.h>
#include <hip/hip_bf16.h>
#include <math.h>

// ---------------- problem constants ----------------
constexpr int NN   = 50000;        // nodes (= 3125 * 16, no MFMA tail)
constexpr int EE   = 400000;       // edges (before self loops)
constexpr int EP   = EE + NN;      // edges + self loops
constexpr int DIN  = 256;          // input dim
constexpr int M1   = 128;          // heads*H1
constexpr int F1   = 32;           // per-head dim layer 1
constexpr int H1N  = 4;            // heads layer 1
constexpr int M2   = 64;           // H2
constexpr int BP   = 4096;         // entity pairs
constexpr int DEC  = 512;          // decoder hidden
constexpr float SLOPE = 0.2f;

// output layout (flat, fp32)
constexpr int O_LOG    = 0;
constexpr int O_RETOS  = 8192;
constexpr int O_RETOSA = 108192;
constexpr int O_X2     = 208192;
constexpr int O_LOGITS = 3408192;
constexpr int O_LOG1   = 3508192;

constexpr int SCAN_NB = (NN + 1023) / 1024;

typedef __attribute__((ext_vector_type(8))) short short8;   // 8 bf16 = 4 VGPRs
typedef __attribute__((ext_vector_type(4))) float f32x4;

__device__ __forceinline__ short f2bs(float v){
    __hip_bfloat16 h = __float2bfloat16(v);
    unsigned short u; __builtin_memcpy(&u, &h, 2);
    return (short)u;
}

// ---------------- CSR build ----------------
__global__ void hist_dst(const int* __restrict__ edst, int* __restrict__ cnt){
    int i = blockIdx.x*blockDim.x + threadIdx.x;
    if (i < EE) atomicAdd(&cnt[edst[i]], 1);
}

__global__ __launch_bounds__(1024) void scan_blk(const int* __restrict__ cnt,
                                                 int* __restrict__ rowex,
                                                 int* __restrict__ bsum){
    __shared__ int wsum[16];
    const int t = threadIdx.x;
    const int idx = blockIdx.x*1024 + t;
    const int lane = t & 63, wid = t >> 6;
    int v = (idx < NN) ? cnt[idx] : 0;
    int s = v;
    #pragma unroll
    for (int o = 1; o < 64; o <<= 1){
        int u = __shfl_up(s, o, 64);
        if (lane >= o) s += u;
    }
    if (lane == 63) wsum[wid] = s;
    __syncthreads();
    if (wid == 0){
        int ws = (lane < 16) ? wsum[lane] : 0;
        #pragma unroll
        for (int o = 1; o < 16; o <<= 1){
            int u = __shfl_up(ws, o, 64);
            if (lane >= o) ws += u;
        }
        if (lane < 16) wsum[lane] = ws;
    }
    __syncthreads();
    int base = (wid > 0) ? wsum[wid-1] : 0;
    int incl = base + s;
    if (idx < NN) rowex[idx] = incl - v;
    if (t == 1023) bsum[blockIdx.x] = incl;
}

__global__ void scan_bsum(int* __restrict__ bsum, int nb){
    const int lane = threadIdx.x;
    int v = (lane < nb) ? bsum[lane] : 0;
    int s = v;
    #pragma unroll
    for (int o = 1; o < 64; o <<= 1){
        int u = __shfl_up(s, o, 64);
        if (lane >= o) s += u;
    }
    if (lane < nb) bsum[lane] = s - v;
}

__global__ void scan_fix(int* __restrict__ row, const int* __restrict__ bsum,
                         int* __restrict__ cursor){
    int idx = blockIdx.x*blockDim.x + threadIdx.x;
    if (idx < NN){
        int r = row[idx] + bsum[idx >> 10];
        row[idx] = r;
        cursor[idx] = r;
    }
    if (idx == 0) row[NN] = EE;
}

__global__ void fill_csr(const int* __restrict__ esrc, const int* __restrict__ edst,
                         int* __restrict__ cursor, int* __restrict__ adj){
    int i = blockIdx.x*blockDim.x + threadIdx.x;
    if (i >= EE) return;
    int d = edst[i];
    int slot = atomicAdd(&cursor[d], 1);
    adj[slot] = esrc[i];
}

// ---------------- W pack: fp32 [K][M] -> bf16 B-fragment layout ----------------
__global__ void pack_w(const float* __restrict__ W, __hip_bfloat16* __restrict__ Wpk,
                       int K, int M){
    int i = blockIdx.x*blockDim.x + threadIdx.x;
    if (i >= K*M) return;
    int k = i / M, c = i - k*M;
    int kb = k >> 5, r = k & 31, quad = r >> 3, j = r & 7;
    int ct = c >> 4, ln = quad*16 + (c & 15);
    int CT = M >> 4;
    size_t dst = (((size_t)kb*CT + ct)*64 + ln)*8 + j;
    Wpk[dst] = __float2bfloat16(W[i]);
}

// ---------------- MFMA GEMM: H = bf16(X @ W), one wave per 16-node tile ------
template<int K, int M, bool AF32>
__global__ __launch_bounds__(256) void gemm_mfma(
        const void* __restrict__ Xv, const __hip_bfloat16* __restrict__ Wpk,
        __hip_bfloat16* __restrict__ Hb){
    constexpr int CT = M/16;
    constexpr int KB = K/32;
    const int wave = (blockIdx.x*256 + threadIdx.x) >> 6;
    const int lane = threadIdx.x & 63;
    const int n0 = wave*16;
    if (n0 >= NN) return;
    const int arow = lane & 15;
    const int quad = lane >> 4;

    f32x4 acc[CT];
    #pragma unroll
    for (int ct = 0; ct < CT; ++ct) acc[ct] = (f32x4){0.f,0.f,0.f,0.f};

    for (int kb = 0; kb < KB; ++kb){
        const int kbase = kb*32 + quad*8;
        short8 af;
        if constexpr (AF32){
            const float* ap = (const float*)Xv + (size_t)(n0 + arow)*K + kbase;
            float4 v0 = *(const float4*)ap;
            float4 v1 = *(const float4*)(ap + 4);
            af[0]=f2bs(v0.x); af[1]=f2bs(v0.y); af[2]=f2bs(v0.z); af[3]=f2bs(v0.w);
            af[4]=f2bs(v1.x); af[5]=f2bs(v1.y); af[6]=f2bs(v1.z); af[7]=f2bs(v1.w);
        } else {
            af = *(const short8*)((const __hip_bfloat16*)Xv + (size_t)(n0 + arow)*K + kbase);
        }
        const __hip_bfloat16* wp = Wpk + (size_t)kb*CT*64*8;
        #pragma unroll
        for (int ct = 0; ct < CT; ++ct){
            short8 bfr = *(const short8*)(wp + ((size_t)ct*64 + lane)*8);
            acc[ct] = __builtin_amdgcn_mfma_f32_16x16x32_bf16(af, bfr, acc[ct], 0, 0, 0);
        }
    }
    #pragma unroll
    for (int ct = 0; ct < CT; ++ct){
        #pragma unroll
        for (int r = 0; r < 4; ++r){
            int n = n0 + quad*4 + r;
            Hb[(size_t)n*M + ct*16 + arow] = __float2bfloat16(acc[ct][r]);
        }
    }
}

// ---------------- attention scores from bf16 H ----------------
template<int M, int F>
__global__ __launch_bounds__(M) void attn_scores(
        const __hip_bfloat16* __restrict__ Hb,
        const float* __restrict__ asrc, const float* __restrict__ adst,
        float* __restrict__ AS, float* __restrict__ AD){
    const int n = blockIdx.x, t = threadIdx.x;
    float h = __bfloat162float(Hb[(size_t)n*M + t]);
    float s1 = h*asrc[t], s2 = h*adst[t];
    #pragma unroll
    for (int o = F>>1; o > 0; o >>= 1){
        s1 += __shfl_down(s1, o, F);
        s2 += __shfl_down(s2, o, F);
    }
    if ((t & (F-1)) == 0){
        AS[(size_t)n*(M/F) + t/F] = s1;
        AD[(size_t)n*(M/F) + t/F] = s2;
    }
}

// ---------------- atomic-free GAT aggregation (bf16 H in) ----------------
template<int M, int F, bool OUTBF>
__global__ __launch_bounds__(M) void gat_aggregate(
        const int* __restrict__ row, const int* __restrict__ adj,
        const __hip_bfloat16* __restrict__ Hfeat,
        const float* __restrict__ AS, const float* __restrict__ AD,
        const float* __restrict__ b, const float* __restrict__ p,
        float* __restrict__ outF, __hip_bfloat16* __restrict__ outB){
    constexpr int NH = M/F;
    const int d = blockIdx.x;
    const int m = threadIdx.x;
    const int h = m / F;
    const float ad = AD[(size_t)d*NH + h];
    float acc = 0.f, den = 0.f;
    {   // self loop
        float e = AS[(size_t)d*NH + h] + ad;
        e = (e >= 0.f) ? e : SLOPE*e;
        float wgt = expf(e);
        acc += __bfloat162float(Hfeat[(size_t)d*M + m]) * wgt;
        den += wgt;
    }
    const int beg = row[d], end = row[d+1];
    for (int j = beg; j < end; ++j){
        int s = adj[j];
        float e = AS[(size_t)s*NH + h] + ad;
        e = (e >= 0.f) ? e : SLOPE*e;
        float wgt = expf(e);
        acc += __bfloat162float(Hfeat[(size_t)s*M + m]) * wgt;
        den += wgt;
    }
    float v = acc/(den + 1e-16f) + b[m];
    float pw = p[m];
    v = (v >= 0.f) ? v : pw*v;
    if constexpr (OUTBF) outB[(size_t)d*M + m] = __float2bfloat16(v);
    else                 outF[(size_t)d*M + m] = v;
}

// ---------------- coalesced column sums: X [NN,64] -> out[64] (pre-zeroed) ----
// thread t: column t&63, row-group t>>6; consecutive lanes -> consecutive cols.
__global__ __launch_bounds__(256) void colsum_fast(const float* __restrict__ X,
                                                   float* __restrict__ out){
    __shared__ float red[256];
    const int t = threadIdx.x;
    const int c = t & 63;
    const int rg = t >> 6;
    float s = 0.f;
    for (int r = blockIdx.x*4 + rg; r < NN; r += gridDim.x*4)
        s += X[(size_t)r*64 + c];
    red[t] = s; __syncthreads();
    if (t < 64){
        float v = red[t] + red[t+64] + red[t+128] + red[t+192];
        atomicAdd(&out[c], v);
    }
}

__global__ void summary(const float* __restrict__ csum_o, const float* __restrict__ csum_a,
                        const float* __restrict__ mlpW, const float* __restrict__ mlpb,
                        const float* __restrict__ discW,
                        const float* __restrict__ advW, const float* __restrict__ advb,
                        float* __restrict__ Wc_o, float* __restrict__ Wc_a,
                        float* __restrict__ advRow, float* __restrict__ advbsum){
    __shared__ float s_o[64], s_a[64], h_o[64], h_a[64];
    const int t = threadIdx.x;
    s_o[t] = 1.f/(1.f + expf(-csum_o[t]/(float)NN));
    s_a[t] = 1.f/(1.f + expf(-csum_a[t]/(float)NN));
    __syncthreads();
    float ao = 0.f, aa = 0.f;
    for (int k = 0; k < 64; ++k){ float w = mlpW[k*64 + t]; ao += s_o[k]*w; aa += s_a[k]*w; }
    float bb = mlpb[t];
    h_o[t] = ao + bb; h_a[t] = aa + bb;
    __syncthreads();
    float wo = 0.f, wa = 0.f;
    for (int j = 0; j < 64; ++j){ float w = discW[t*64 + j]; wo += w*h_o[j]; wa += w*h_a[j]; }
    Wc_o[t] = wo; Wc_a[t] = wa;
    float ar = 0.f;
    for (int j = 0; j < 64; ++j) ar += advW[t*64 + j];
    advRow[t] = ar;
    float ab = advb[t];
    for (int o = 32; o > 0; o >>= 1) ab += __shfl_down(ab, o, 64);
    if (t == 0) advbsum[0] = ab;
}

__global__ void node_outputs(const float* __restrict__ x2o, const float* __restrict__ x2a,
                             const float* __restrict__ Wc_o, const float* __restrict__ Wc_a,
                             const float* __restrict__ advRow, const float* __restrict__ advbsum,
                             const float* __restrict__ discb,
                             float* __restrict__ out){
    const int n = blockIdx.x*4 + (threadIdx.x >> 6);
    const int l = threadIdx.x & 63;
    float xo = x2o[(size_t)n*64 + l], xa = x2a[(size_t)n*64 + l];
    float wo = Wc_o[l], wa = Wc_a[l], ar = advRow[l];
    float d1 = xo*wo, d2 = xa*wo, d3 = xa*wa, d4 = xo*wa, d5 = xo*ar, d6 = xa*ar;
    for (int o = 32; o > 0; o >>= 1){
        d1 += __shfl_down(d1, o, 64); d2 += __shfl_down(d2, o, 64);
        d3 += __shfl_down(d3, o, 64); d4 += __shfl_down(d4, o, 64);
        d5 += __shfl_down(d5, o, 64); d6 += __shfl_down(d6, o, 64);
    }
    out[O_X2 + (size_t)n*64 + l] = xo;
    if (l == 0){
        float db = discb[0];
        float ab = advbsum[0];
        out[O_RETOS  + n*2 + 0] = d1 + db;
        out[O_RETOS  + n*2 + 1] = d2 + db;
        out[O_RETOSA + n*2 + 0] = d3 + db;
        out[O_RETOSA + n*2 + 1] = d4 + db;
        out[O_LOGITS + n]       = d5 + ab;
        out[O_LOGITS + NN + n]  = d6 + ab;
    }
}

__global__ void decoder1(const float* __restrict__ x2o, const int* __restrict__ idxArr,
                         const float* __restrict__ fW1, const float* __restrict__ fb1,
                         float* __restrict__ fh){
    __shared__ float e[128];
    const int b = blockIdx.x, t = threadIdx.x;
    const int i0 = idxArr[b], i1 = idxArr[BP + b];
    if (t < 64)        e[t] = x2o[(size_t)i0*64 + t];
    else if (t < 128)  e[t] = x2o[(size_t)i1*64 + (t - 64)];
    __syncthreads();
    for (int mm = t; mm < DEC; mm += 256){
        float acc = 0.f;
        #pragma unroll 8
        for (int k = 0; k < 128; ++k) acc += e[k] * fW1[(size_t)k*DEC + mm];
        acc += fb1[mm];
        fh[(size_t)b*DEC + mm] = (acc > 0.f) ? acc : 0.f;
    }
}

__global__ void decoder2(const float* __restrict__ fh,
                         const float* __restrict__ fW2, const float* __restrict__ fb2,
                         const float* __restrict__ fW3, const float* __restrict__ fb3,
                         float* __restrict__ out){
    const int b = blockIdx.x, t = threadIdx.x;
    float a0 = 0.f, a1 = 0.f, c0 = 0.f, c1 = 0.f;
    for (int m = t; m < DEC; m += 64){
        float v = fh[(size_t)b*DEC + m];
        a0 += v*fW2[m*2 + 0]; a1 += v*fW2[m*2 + 1];
        c0 += v*fW3[m*2 + 0]; c1 += v*fW3[m*2 + 1];
    }
    for (int o = 32; o > 0; o >>= 1){
        a0 += __shfl_down(a0, o, 64); a1 += __shfl_down(a1, o, 64);
        c0 += __shfl_down(c0, o, 64); c1 += __shfl_down(c1, o, 64);
    }
    if (t == 0){
        out[O_LOG  + b*2 + 0] = a0 + fb2[0];
        out[O_LOG  + b*2 + 1] = a1 + fb2[1];
        out[O_LOG1 + b*2 + 0] = c0 + fb3[0];
        out[O_LOG1 + b*2 + 1] = c1 + fb3[1];
    }
}

extern "C" void kernel_launch(void* const* d_in, const int* in_sizes, int n_in,
                              void* d_out, int out_size, void* d_ws, size_t ws_size,
                              hipStream_t stream){
    const float* x_o    = (const float*)d_in[0];
    const float* x_a    = (const float*)d_in[1];
    const int*   edge   = (const int*)d_in[2];
    const int*   idxp   = (const int*)d_in[3];
    const float* W1     = (const float*)d_in[4];
    const float* a_src1 = (const float*)d_in[5];
    const float* a_dst1 = (const float*)d_in[6];
    const float* b1     = (const float*)d_in[7];
    const float* p1     = (const float*)d_in[8];
    const float* W2     = (const float*)d_in[9];
    const float* a_src2 = (const float*)d_in[10];
    const float* a_dst2 = (const float*)d_in[11];
    const float* b2     = (const float*)d_in[12];
    const float* p2     = (const float*)d_in[13];
    const float* mlpW   = (const float*)d_in[14];
    const float* mlpb   = (const float*)d_in[15];
    const float* discW  = (const float*)d_in[16];
    const float* discb  = (const float*)d_in[17];
    const float* advW   = (const float*)d_in[18];
    const float* advb   = (const float*)d_in[19];
    const float* fW1    = (const float*)d_in[20];
    const float* fb1    = (const float*)d_in[21];
    const float* fW2    = (const float*)d_in[22];
    const float* fb2    = (const float*)d_in[23];
    const float* fW3    = (const float*)d_in[24];
    const float* fb3    = (const float*)d_in[25];

    const int* esrc = edge;
    const int* edst = edge + EE;

    // workspace carve-up (fp32 units), ~60 MB total
    float* w = (float*)d_ws;
    size_t off = 0;
    auto alloc = [&](size_t nfloats){ float* p = w + off; off += nfloats; return p; };
    __hip_bfloat16* Hb   = (__hip_bfloat16*)alloc((size_t)NN*M1/2);  // H bf16; fh aliases later
    __hip_bfloat16* x1b  = (__hip_bfloat16*)alloc((size_t)NN*M1/2);  // layer-1 out, bf16
    float* asb   = alloc((size_t)NN*H1N);
    float* adb   = alloc((size_t)NN*H1N);
    float* x2o   = alloc((size_t)NN*M2);
    float* x2a   = alloc((size_t)NN*M2);
    __hip_bfloat16* Wpk1 = (__hip_bfloat16*)alloc((size_t)DIN*M1/2);
    __hip_bfloat16* Wpk2 = (__hip_bfloat16*)alloc((size_t)M1*M2/2);
    int*   cnt   = (int*)alloc(NN);
    int*   row   = (int*)alloc(NN + 1);
    int*   cursor= (int*)alloc(NN);
    int*   adj   = (int*)alloc(EE);
    int*   bsum  = (int*)alloc(SCAN_NB + 1);
    float* smallb= alloc(512);
    float* fh     = (float*)Hb;            // decoder scratch after encoders done
    float* csum_o = smallb;       float* csum_a = smallb + 64;
    float* Wc_o   = smallb + 128; float* Wc_a   = smallb + 192;
    float* advRow = smallb + 256; float* advbs  = smallb + 320;

    float* out = (float*)d_out;

    // ---- CSR build + W packing (once) ----
    hipMemsetAsync(cnt, 0, NN*sizeof(int), stream);
    hipMemsetAsync(smallb, 0, 128*sizeof(float), stream);   // csum_o / csum_a
    hist_dst<<<(EE + 255)/256, 256, 0, stream>>>(edst, cnt);
    scan_blk<<<SCAN_NB, 1024, 0, stream>>>(cnt, row, bsum);
    scan_bsum<<<1, 64, 0, stream>>>(bsum, SCAN_NB);
    scan_fix<<<(NN + 255)/256, 256, 0, stream>>>(row, bsum, cursor);
    fill_csr<<<(EE + 255)/256, 256, 0, stream>>>(esrc, edst, cursor, adj);
    pack_w<<<(DIN*M1 + 255)/256, 256, 0, stream>>>(W1, Wpk1, DIN, M1);
    pack_w<<<(M1*M2 + 255)/256, 256, 0, stream>>>(W2, Wpk2, M1, M2);

    const int gw = ((NN/16) + 3) / 4;   // 3125 waves, 4 per block

    auto run_encoder = [&](const float* xin, float* x2out){
        // ---- layer 1: D=256 -> 4 heads x 32 ----
        gemm_mfma<DIN, M1, true><<<gw, 256, 0, stream>>>(xin, Wpk1, Hb);
        attn_scores<M1, F1><<<NN, M1, 0, stream>>>(Hb, a_src1, a_dst1, asb, adb);
        gat_aggregate<M1, F1, true><<<NN, M1, 0, stream>>>(
            row, adj, Hb, asb, adb, b1, p1, nullptr, x1b);

        // ---- layer 2: 128 -> 64, 1 head ----
        gemm_mfma<M1, M2, false><<<gw, 256, 0, stream>>>(x1b, Wpk2, Hb);
        attn_scores<M2, M2><<<NN, M2, 0, stream>>>(Hb, a_src2, a_dst2, asb, adb);
        gat_aggregate<M2, M2, false><<<NN, M2, 0, stream>>>(
            row, adj, Hb, asb, adb, b2, p2, x2out, nullptr);
    };

    run_encoder(x_o, x2o);
    run_encoder(x_a, x2a);

    colsum_fast<<<256, 256, 0, stream>>>(x2o, csum_o);
    colsum_fast<<<256, 256, 0, stream>>>(x2a, csum_a);
    summary<<<1, 64, 0, stream>>>(csum_o, csum_a, mlpW, mlpb, discW, advW, advb,
                                  Wc_o, Wc_a, advRow, advbs);
    node_outputs<<<NN/4, 256, 0, stream>>>(x2o, x2a, Wc_o, Wc_a, advRow, advbs, discb, out);
    decoder1<<<BP, 256, 0, stream>>>(x2o, idxp, fW1, fb1, fh);
    decoder2<<<BP, 64, 0, stream>>>(fh, fW2, fb2, fW3, fb3, out);
}

// Round 11
// 595.619 us; speedup vs baseline: 5.0748x; 1.0452x over previous
//
#include <hip/hip_runtime.h>
#include <hip/hip_bf16.h>
#include <math.h>

// ---------------- problem constants ----------------
constexpr int NN   = 50000;        // nodes (= 3125 * 16, no MFMA tail)
constexpr int EE   = 400000;       // edges (before self loops)
constexpr int EP   = EE + NN;      // edges + self loops
constexpr int DIN  = 256;          // input dim
constexpr int M1   = 128;          // heads*H1
constexpr int F1   = 32;           // per-head dim layer 1
constexpr int H1N  = 4;            // heads layer 1
constexpr int M2   = 64;           // H2
constexpr int BP   = 4096;         // entity pairs
constexpr int DEC  = 512;          // decoder hidden
constexpr float SLOPE = 0.2f;

// output layout (flat, fp32)
constexpr int O_LOG    = 0;
constexpr int O_RETOS  = 8192;
constexpr int O_RETOSA = 108192;
constexpr int O_X2     = 208192;
constexpr int O_LOGITS = 3408192;
constexpr int O_LOG1   = 3508192;

constexpr int SCAN_NB = (NN + 1023) / 1024;

typedef __attribute__((ext_vector_type(8))) short short8;   // 8 bf16 = 4 VGPRs
typedef __attribute__((ext_vector_type(4))) float f32x4;

__device__ __forceinline__ short f2bs(float v){
    __hip_bfloat16 h = __float2bfloat16(v);
    unsigned short u; __builtin_memcpy(&u, &h, 2);
    return (short)u;
}
__device__ __forceinline__ float lrelu(float e){ return (e >= 0.f) ? e : SLOPE*e; }

// ---------------- CSR build ----------------
__global__ void hist_dst(const int* __restrict__ edst, int* __restrict__ cnt){
    int i = blockIdx.x*blockDim.x + threadIdx.x;
    if (i < EE) atomicAdd(&cnt[edst[i]], 1);
}

__global__ __launch_bounds__(1024) void scan_blk(const int* __restrict__ cnt,
                                                 int* __restrict__ rowex,
                                                 int* __restrict__ bsum){
    __shared__ int wsum[16];
    const int t = threadIdx.x;
    const int idx = blockIdx.x*1024 + t;
    const int lane = t & 63, wid = t >> 6;
    int v = (idx < NN) ? cnt[idx] : 0;
    int s = v;
    #pragma unroll
    for (int o = 1; o < 64; o <<= 1){
        int u = __shfl_up(s, o, 64);
        if (lane >= o) s += u;
    }
    if (lane == 63) wsum[wid] = s;
    __syncthreads();
    if (wid == 0){
        int ws = (lane < 16) ? wsum[lane] : 0;
        #pragma unroll
        for (int o = 1; o < 16; o <<= 1){
            int u = __shfl_up(ws, o, 64);
            if (lane >= o) ws += u;
        }
        if (lane < 16) wsum[lane] = ws;
    }
    __syncthreads();
    int base = (wid > 0) ? wsum[wid-1] : 0;
    int incl = base + s;
    if (idx < NN) rowex[idx] = incl - v;
    if (t == 1023) bsum[blockIdx.x] = incl;
}

__global__ void scan_bsum(int* __restrict__ bsum, int nb){
    const int lane = threadIdx.x;
    int v = (lane < nb) ? bsum[lane] : 0;
    int s = v;
    #pragma unroll
    for (int o = 1; o < 64; o <<= 1){
        int u = __shfl_up(s, o, 64);
        if (lane >= o) s += u;
    }
    if (lane < nb) bsum[lane] = s - v;
}

__global__ void scan_fix(int* __restrict__ row, const int* __restrict__ bsum,
                         int* __restrict__ cursor){
    int idx = blockIdx.x*blockDim.x + threadIdx.x;
    if (idx < NN){
        int r = row[idx] + bsum[idx >> 10];
        row[idx] = r;
        cursor[idx] = r;
    }
    if (idx == 0) row[NN] = EE;
}

__global__ void fill_csr(const int* __restrict__ esrc, const int* __restrict__ edst,
                         int* __restrict__ cursor, int* __restrict__ adj,
                         int* __restrict__ dcsr){
    int i = blockIdx.x*blockDim.x + threadIdx.x;
    if (i >= EE) return;
    int d = edst[i];
    int slot = atomicAdd(&cursor[d], 1);
    adj[slot] = esrc[i];
    dcsr[slot] = d;
}

// ---------------- W pack: fp32 [K][M] -> bf16 B-fragment layout ----------------
__global__ void pack_w(const float* __restrict__ W, __hip_bfloat16* __restrict__ Wpk,
                       int K, int M){
    int i = blockIdx.x*blockDim.x + threadIdx.x;
    if (i >= K*M) return;
    int k = i / M, c = i - k*M;
    int kb = k >> 5, r = k & 31, quad = r >> 3, j = r & 7;
    int ct = c >> 4, ln = quad*16 + (c & 15);
    int CT = M >> 4;
    size_t dst = (((size_t)kb*CT + ct)*64 + ln)*8 + j;
    Wpk[dst] = __float2bfloat16(W[i]);
}

// ---------------- MFMA GEMM: H = bf16(X @ W), one wave per 16-node tile ------
template<int K, int M, bool AF32>
__global__ __launch_bounds__(256) void gemm_mfma(
        const void* __restrict__ Xv, const __hip_bfloat16* __restrict__ Wpk,
        __hip_bfloat16* __restrict__ Hb){
    constexpr int CT = M/16;
    constexpr int KB = K/32;
    const int wave = (blockIdx.x*256 + threadIdx.x) >> 6;
    const int lane = threadIdx.x & 63;
    const int n0 = wave*16;
    if (n0 >= NN) return;
    const int arow = lane & 15;
    const int quad = lane >> 4;

    f32x4 acc[CT];
    #pragma unroll
    for (int ct = 0; ct < CT; ++ct) acc[ct] = (f32x4){0.f,0.f,0.f,0.f};

    for (int kb = 0; kb < KB; ++kb){
        const int kbase = kb*32 + quad*8;
        short8 af;
        if constexpr (AF32){
            const float* ap = (const float*)Xv + (size_t)(n0 + arow)*K + kbase;
            float4 v0 = *(const float4*)ap;
            float4 v1 = *(const float4*)(ap + 4);
            af[0]=f2bs(v0.x); af[1]=f2bs(v0.y); af[2]=f2bs(v0.z); af[3]=f2bs(v0.w);
            af[4]=f2bs(v1.x); af[5]=f2bs(v1.y); af[6]=f2bs(v1.z); af[7]=f2bs(v1.w);
        } else {
            af = *(const short8*)((const __hip_bfloat16*)Xv + (size_t)(n0 + arow)*K + kbase);
        }
        const __hip_bfloat16* wp = Wpk + (size_t)kb*CT*64*8;
        #pragma unroll
        for (int ct = 0; ct < CT; ++ct){
            short8 bfr = *(const short8*)(wp + ((size_t)ct*64 + lane)*8);
            acc[ct] = __builtin_amdgcn_mfma_f32_16x16x32_bf16(af, bfr, acc[ct], 0, 0, 0);
        }
    }
    #pragma unroll
    for (int ct = 0; ct < CT; ++ct){
        #pragma unroll
        for (int r = 0; r < 4; ++r){
            int n = n0 + quad*4 + r;
            Hb[(size_t)n*M + ct*16 + arow] = __float2bfloat16(acc[ct][r]);
        }
    }
}

// ---------------- attention scores from bf16 H ----------------
template<int M, int F>
__global__ __launch_bounds__(M) void attn_scores(
        const __hip_bfloat16* __restrict__ Hb,
        const float* __restrict__ asrc, const float* __restrict__ adst,
        float* __restrict__ AS, float* __restrict__ AD){
    const int n = blockIdx.x, t = threadIdx.x;
    float h = __bfloat162float(Hb[(size_t)n*M + t]);
    float s1 = h*asrc[t], s2 = h*adst[t];
    #pragma unroll
    for (int o = F>>1; o > 0; o >>= 1){
        s1 += __shfl_down(s1, o, F);
        s2 += __shfl_down(s2, o, F);
    }
    if ((t & (F-1)) == 0){
        AS[(size_t)n*(M/F) + t/F] = s1;
        AD[(size_t)n*(M/F) + t/F] = s2;
    }
}

// ---------------- per-edge softmax weights (CSR slot order) ----------------
// Softmax without max-subtraction: scores O(+-10), exp fp32-safe, alpha identical.
__global__ void edge_w4(const int* __restrict__ adj, const int* __restrict__ dcsr,
                        const float* __restrict__ AS, const float* __restrict__ AD,
                        float* __restrict__ wbuf){
    int i = blockIdx.x*blockDim.x + threadIdx.x;
    if (i >= EE) return;
    int s = adj[i], d = dcsr[i];
    float4 as = *(const float4*)(AS + (size_t)s*4);
    float4 ad = *(const float4*)(AD + (size_t)d*4);
    float4 w;
    w.x = expf(lrelu(as.x + ad.x));
    w.y = expf(lrelu(as.y + ad.y));
    w.z = expf(lrelu(as.z + ad.z));
    w.w = expf(lrelu(as.w + ad.w));
    *(float4*)(wbuf + (size_t)i*4) = w;
}

__global__ void edge_w1(const int* __restrict__ adj, const int* __restrict__ dcsr,
                        const float* __restrict__ AS, const float* __restrict__ AD,
                        float* __restrict__ wbuf){
    int i = blockIdx.x*blockDim.x + threadIdx.x;
    if (i >= EE) return;
    wbuf[i] = expf(lrelu(AS[adj[i]] + AD[dcsr[i]]));
}

// ---------------- atomic-free GAT aggregation, precomputed weights ----------
// Layer 1 (M=128, F=32): 64 threads/block, 2 bf16 cols per thread (dword load,
// bit-shift unpack, no cvt). Weight per edge comes from wbuf (CSR slot order).
__global__ __launch_bounds__(64) void gat_agg_l1(
        const int* __restrict__ row, const int* __restrict__ adj,
        const float* __restrict__ wbuf,
        const __hip_bfloat16* __restrict__ Hfeat,
        const float* __restrict__ AS, const float* __restrict__ AD,
        const float* __restrict__ b, const float* __restrict__ p,
        __hip_bfloat16* __restrict__ outB){
    const int d = blockIdx.x;
    const int t = threadIdx.x;          // col pair t -> cols 2t, 2t+1
    const int h = t >> 4;               // 32 cols per head -> 16 threads per head
    const unsigned* Hw = (const unsigned*)Hfeat;
    float acc0 = 0.f, acc1 = 0.f, den = 0.f;
    {   // self loop
        float ws = expf(lrelu(AS[(size_t)d*4 + h] + AD[(size_t)d*4 + h]));
        unsigned u = Hw[(size_t)d*64 + t];
        acc0 += __uint_as_float(u << 16) * ws;
        acc1 += __uint_as_float(u & 0xffff0000u) * ws;
        den += ws;
    }
    const int beg = row[d], end = row[d+1];
    for (int j = beg; j < end; ++j){
        int s = adj[j];
        float wgt = wbuf[(size_t)j*4 + h];
        unsigned u = Hw[(size_t)s*64 + t];
        acc0 += __uint_as_float(u << 16) * wgt;
        acc1 += __uint_as_float(u & 0xffff0000u) * wgt;
        den += wgt;
    }
    float inv = 1.f/(den + 1e-16f);
    float v0 = acc0*inv + b[2*t];
    float v1 = acc1*inv + b[2*t+1];
    v0 = (v0 >= 0.f) ? v0 : p[2*t]*v0;
    v1 = (v1 >= 0.f) ? v1 : p[2*t+1]*v1;
    ushort2 st = make_ushort2((unsigned short)f2bs(v0), (unsigned short)f2bs(v1));
    *(ushort2*)(outB + (size_t)d*128 + 2*t) = st;
}

// Layer 2 (M=64, 1 head): 64 threads/block, 1 col each.
__global__ __launch_bounds__(64) void gat_agg_l2(
        const int* __restrict__ row, const int* __restrict__ adj,
        const float* __restrict__ wbuf,
        const __hip_bfloat16* __restrict__ Hfeat,
        const float* __restrict__ AS, const float* __restrict__ AD,
        const float* __restrict__ b, const float* __restrict__ p,
        float* __restrict__ outF){
    const int d = blockIdx.x;
    const int t = threadIdx.x;
    float acc = 0.f, den = 0.f;
    {   // self loop
        float ws = expf(lrelu(AS[d] + AD[d]));
        acc += __bfloat162float(Hfeat[(size_t)d*64 + t]) * ws;
        den += ws;
    }
    const int beg = row[d], end = row[d+1];
    for (int j = beg; j < end; ++j){
        int s = adj[j];
        float wgt = wbuf[j];
        acc += __bfloat162float(Hfeat[(size_t)s*64 + t]) * wgt;
        den += wgt;
    }
    float v = acc/(den + 1e-16f) + b[t];
    outF[(size_t)d*64 + t] = (v >= 0.f) ? v : p[t]*v;
}

// ---------------- coalesced column sums: X [NN,64] -> out[64] (pre-zeroed) ----
__global__ __launch_bounds__(256) void colsum_fast(const float* __restrict__ X,
                                                   float* __restrict__ out){
    __shared__ float red[256];
    const int t = threadIdx.x;
    const int c = t & 63;
    const int rg = t >> 6;
    float s = 0.f;
    for (int r = blockIdx.x*4 + rg; r < NN; r += gridDim.x*4)
        s += X[(size_t)r*64 + c];
    red[t] = s; __syncthreads();
    if (t < 64){
        float v = red[t] + red[t+64] + red[t+128] + red[t+192];
        atomicAdd(&out[c], v);
    }
}

__global__ void summary(const float* __restrict__ csum_o, const float* __restrict__ csum_a,
                        const float* __restrict__ mlpW, const float* __restrict__ mlpb,
                        const float* __restrict__ discW,
                        const float* __restrict__ advW, const float* __restrict__ advb,
                        float* __restrict__ Wc_o, float* __restrict__ Wc_a,
                        float* __restrict__ advRow, float* __restrict__ advbsum){
    __shared__ float s_o[64], s_a[64], h_o[64], h_a[64];
    const int t = threadIdx.x;
    s_o[t] = 1.f/(1.f + expf(-csum_o[t]/(float)NN));
    s_a[t] = 1.f/(1.f + expf(-csum_a[t]/(float)NN));
    __syncthreads();
    float ao = 0.f, aa = 0.f;
    for (int k = 0; k < 64; ++k){ float w = mlpW[k*64 + t]; ao += s_o[k]*w; aa += s_a[k]*w; }
    float bb = mlpb[t];
    h_o[t] = ao + bb; h_a[t] = aa + bb;
    __syncthreads();
    float wo = 0.f, wa = 0.f;
    for (int j = 0; j < 64; ++j){ float w = discW[t*64 + j]; wo += w*h_o[j]; wa += w*h_a[j]; }
    Wc_o[t] = wo; Wc_a[t] = wa;
    float ar = 0.f;
    for (int j = 0; j < 64; ++j) ar += advW[t*64 + j];
    advRow[t] = ar;
    float ab = advb[t];
    for (int o = 32; o > 0; o >>= 1) ab += __shfl_down(ab, o, 64);
    if (t == 0) advbsum[0] = ab;
}

__global__ void node_outputs(const float* __restrict__ x2o, const float* __restrict__ x2a,
                             const float* __restrict__ Wc_o, const float* __restrict__ Wc_a,
                             const float* __restrict__ advRow, const float* __restrict__ advbsum,
                             const float* __restrict__ discb,
                             float* __restrict__ out){
    const int n = blockIdx.x*4 + (threadIdx.x >> 6);
    const int l = threadIdx.x & 63;
    float xo = x2o[(size_t)n*64 + l], xa = x2a[(size_t)n*64 + l];
    float wo = Wc_o[l], wa = Wc_a[l], ar = advRow[l];
    float d1 = xo*wo, d2 = xa*wo, d3 = xa*wa, d4 = xo*wa, d5 = xo*ar, d6 = xa*ar;
    for (int o = 32; o > 0; o >>= 1){
        d1 += __shfl_down(d1, o, 64); d2 += __shfl_down(d2, o, 64);
        d3 += __shfl_down(d3, o, 64); d4 += __shfl_down(d4, o, 64);
        d5 += __shfl_down(d5, o, 64); d6 += __shfl_down(d6, o, 64);
    }
    out[O_X2 + (size_t)n*64 + l] = xo;
    if (l == 0){
        float db = discb[0];
        float ab = advbsum[0];
        out[O_RETOS  + n*2 + 0] = d1 + db;
        out[O_RETOS  + n*2 + 1] = d2 + db;
        out[O_RETOSA + n*2 + 0] = d3 + db;
        out[O_RETOSA + n*2 + 1] = d4 + db;
        out[O_LOGITS + n]       = d5 + ab;
        out[O_LOGITS + NN + n]  = d6 + ab;
    }
}

__global__ void decoder1(const float* __restrict__ x2o, const int* __restrict__ idxArr,
                         const float* __restrict__ fW1, const float* __restrict__ fb1,
                         float* __restrict__ fh){
    __shared__ float e[128];
    const int b = blockIdx.x, t = threadIdx.x;
    const int i0 = idxArr[b], i1 = idxArr[BP + b];
    if (t < 64)        e[t] = x2o[(size_t)i0*64 + t];
    else if (t < 128)  e[t] = x2o[(size_t)i1*64 + (t - 64)];
    __syncthreads();
    for (int mm = t; mm < DEC; mm += 256){
        float acc = 0.f;
        #pragma unroll 8
        for (int k = 0; k < 128; ++k) acc += e[k] * fW1[(size_t)k*DEC + mm];
        acc += fb1[mm];
        fh[(size_t)b*DEC + mm] = (acc > 0.f) ? acc : 0.f;
    }
}

__global__ void decoder2(const float* __restrict__ fh,
                         const float* __restrict__ fW2, const float* __restrict__ fb2,
                         const float* __restrict__ fW3, const float* __restrict__ fb3,
                         float* __restrict__ out){
    const int b = blockIdx.x, t = threadIdx.x;
    float a0 = 0.f, a1 = 0.f, c0 = 0.f, c1 = 0.f;
    for (int m = t; m < DEC; m += 64){
        float v = fh[(size_t)b*DEC + m];
        a0 += v*fW2[m*2 + 0]; a1 += v*fW2[m*2 + 1];
        c0 += v*fW3[m*2 + 0]; c1 += v*fW3[m*2 + 1];
    }
    for (int o = 32; o > 0; o >>= 1){
        a0 += __shfl_down(a0, o, 64); a1 += __shfl_down(a1, o, 64);
        c0 += __shfl_down(c0, o, 64); c1 += __shfl_down(c1, o, 64);
    }
    if (t == 0){
        out[O_LOG  + b*2 + 0] = a0 + fb2[0];
        out[O_LOG  + b*2 + 1] = a1 + fb2[1];
        out[O_LOG1 + b*2 + 0] = c0 + fb3[0];
        out[O_LOG1 + b*2 + 1] = c1 + fb3[1];
    }
}

extern "C" void kernel_launch(void* const* d_in, const int* in_sizes, int n_in,
                              void* d_out, int out_size, void* d_ws, size_t ws_size,
                              hipStream_t stream){
    const float* x_o    = (const float*)d_in[0];
    const float* x_a    = (const float*)d_in[1];
    const int*   edge   = (const int*)d_in[2];
    const int*   idxp   = (const int*)d_in[3];
    const float* W1     = (const float*)d_in[4];
    const float* a_src1 = (const float*)d_in[5];
    const float* a_dst1 = (const float*)d_in[6];
    const float* b1     = (const float*)d_in[7];
    const float* p1     = (const float*)d_in[8];
    const float* W2     = (const float*)d_in[9];
    const float* a_src2 = (const float*)d_in[10];
    const float* a_dst2 = (const float*)d_in[11];
    const float* b2     = (const float*)d_in[12];
    const float* p2     = (const float*)d_in[13];
    const float* mlpW   = (const float*)d_in[14];
    const float* mlpb   = (const float*)d_in[15];
    const float* discW  = (const float*)d_in[16];
    const float* discb  = (const float*)d_in[17];
    const float* advW   = (const float*)d_in[18];
    const float* advb   = (const float*)d_in[19];
    const float* fW1    = (const float*)d_in[20];
    const float* fb1    = (const float*)d_in[21];
    const float* fW2    = (const float*)d_in[22];
    const float* fb2    = (const float*)d_in[23];
    const float* fW3    = (const float*)d_in[24];
    const float* fb3    = (const float*)d_in[25];

    const int* esrc = edge;
    const int* edst = edge + EE;

    // workspace carve-up (fp32 units), ~70 MB total
    float* w = (float*)d_ws;
    size_t off = 0;
    auto alloc = [&](size_t nfloats){ float* p = w + off; off += nfloats; return p; };
    __hip_bfloat16* Hb   = (__hip_bfloat16*)alloc((size_t)NN*M1/2);  // H bf16; fh aliases later
    __hip_bfloat16* x1b  = (__hip_bfloat16*)alloc((size_t)NN*M1/2);  // layer-1 out, bf16
    float* asb   = alloc((size_t)NN*H1N);
    float* adb   = alloc((size_t)NN*H1N);
    float* x2o   = alloc((size_t)NN*M2);
    float* x2a   = alloc((size_t)NN*M2);
    float* wbuf  = alloc((size_t)EE*H1N);   // per-edge softmax weights (CSR order)
    __hip_bfloat16* Wpk1 = (__hip_bfloat16*)alloc((size_t)DIN*M1/2);
    __hip_bfloat16* Wpk2 = (__hip_bfloat16*)alloc((size_t)M1*M2/2);
    int*   cnt   = (int*)alloc(NN);
    int*   row   = (int*)alloc(NN + 1);
    int*   cursor= (int*)alloc(NN);
    int*   adj   = (int*)alloc(EE);
    int*   dcsr  = (int*)alloc(EE);
    int*   bsum  = (int*)alloc(SCAN_NB + 1);
    float* smallb= alloc(512);
    float* fh     = (float*)Hb;            // decoder scratch after encoders done
    float* csum_o = smallb;       float* csum_a = smallb + 64;
    float* Wc_o   = smallb + 128; float* Wc_a   = smallb + 192;
    float* advRow = smallb + 256; float* advbs  = smallb + 320;

    float* out = (float*)d_out;

    // ---- CSR build + W packing (once) ----
    hipMemsetAsync(cnt, 0, NN*sizeof(int), stream);
    hipMemsetAsync(smallb, 0, 128*sizeof(float), stream);   // csum_o / csum_a
    hist_dst<<<(EE + 255)/256, 256, 0, stream>>>(edst, cnt);
    scan_blk<<<SCAN_NB, 1024, 0, stream>>>(cnt, row, bsum);
    scan_bsum<<<1, 64, 0, stream>>>(bsum, SCAN_NB);
    scan_fix<<<(NN + 255)/256, 256, 0, stream>>>(row, bsum, cursor);
    fill_csr<<<(EE + 255)/256, 256, 0, stream>>>(esrc, edst, cursor, adj, dcsr);
    pack_w<<<(DIN*M1 + 255)/256, 256, 0, stream>>>(W1, Wpk1, DIN, M1);
    pack_w<<<(M1*M2 + 255)/256, 256, 0, stream>>>(W2, Wpk2, M1, M2);

    const int gw = ((NN/16) + 3) / 4;   // 3125 waves, 4 per block
    const int ge = (EE + 255)/256;

    auto run_encoder = [&](const float* xin, float* x2out){
        // ---- layer 1: D=256 -> 4 heads x 32 ----
        gemm_mfma<DIN, M1, true><<<gw, 256, 0, stream>>>(xin, Wpk1, Hb);
        attn_scores<M1, F1><<<NN, M1, 0, stream>>>(Hb, a_src1, a_dst1, asb, adb);
        edge_w4<<<ge, 256, 0, stream>>>(adj, dcsr, asb, adb, wbuf);
        gat_agg_l1<<<NN, 64, 0, stream>>>(row, adj, wbuf, Hb, asb, adb, b1, p1, x1b);

        // ---- layer 2: 128 -> 64, 1 head ----
        gemm_mfma<M1, M2, false><<<gw, 256, 0, stream>>>(x1b, Wpk2, Hb);
        attn_scores<M2, M2><<<NN, M2, 0, stream>>>(Hb, a_src2, a_dst2, asb, adb);
        edge_w1<<<ge, 256, 0, stream>>>(adj, dcsr, asb, adb, wbuf);
        gat_agg_l2<<<NN, 64, 0, stream>>>(row, adj, wbuf, Hb, asb, adb, b2, p2, x2out);
    };

    run_encoder(x_o, x2o);
    run_encoder(x_a, x2a);

    colsum_fast<<<256, 256, 0, stream>>>(x2o, csum_o);
    colsum_fast<<<256, 256, 0, stream>>>(x2a, csum_a);
    summary<<<1, 64, 0, stream>>>(csum_o, csum_a, mlpW, mlpb, discW, advW, advb,
                                  Wc_o, Wc_a, advRow, advbs);
    node_outputs<<<NN/4, 256, 0, stream>>>(x2o, x2a, Wc_o, Wc_a, advRow, advbs, discb, out);
    decoder1<<<BP, 256, 0, stream>>>(x2o, idxp, fW1, fb1, fh);
    decoder2<<<BP, 64, 0, stream>>>(fh, fW2, fb2, fW3, fb3, out);
}

// Round 12
// 564.366 us; speedup vs baseline: 5.3559x; 1.0554x over previous
//
#include <hip/hip_runtime.h>
#include <hip/hip_bf16.h>
#include <math.h>

// ---------------- problem constants ----------------
constexpr int NN   = 50000;        // nodes (= 3125 * 16, no MFMA tail)
constexpr int EE   = 400000;       // edges (before self loops)
constexpr int EP   = EE + NN;      // edges + self loops
constexpr int DIN  = 256;          // input dim
constexpr int M1   = 128;          // heads*H1
constexpr int F1   = 32;           // per-head dim layer 1
constexpr int H1N  = 4;            // heads layer 1
constexpr int M2   = 64;           // H2
constexpr int BP   = 4096;         // entity pairs
constexpr int DEC  = 512;          // decoder hidden
constexpr float SLOPE = 0.2f;

// output layout (flat, fp32)
constexpr int O_LOG    = 0;
constexpr int O_RETOS  = 8192;
constexpr int O_RETOSA = 108192;
constexpr int O_X2     = 208192;
constexpr int O_LOGITS = 3408192;
constexpr int O_LOG1   = 3508192;

constexpr int SCAN_NB = (NN + 1023) / 1024;

typedef __attribute__((ext_vector_type(8))) short short8;   // 8 bf16 = 4 VGPRs
typedef __attribute__((ext_vector_type(4))) float f32x4;

__device__ __forceinline__ short f2bs(float v){
    __hip_bfloat16 h = __float2bfloat16(v);
    unsigned short u; __builtin_memcpy(&u, &h, 2);
    return (short)u;
}
__device__ __forceinline__ float lrelu(float e){ return (e >= 0.f) ? e : SLOPE*e; }

// ---------------- CSR build ----------------
__global__ void hist_dst(const int* __restrict__ edst, int* __restrict__ cnt){
    int i = blockIdx.x*blockDim.x + threadIdx.x;
    if (i < EE) atomicAdd(&cnt[edst[i]], 1);
}

__global__ __launch_bounds__(1024) void scan_blk(const int* __restrict__ cnt,
                                                 int* __restrict__ rowex,
                                                 int* __restrict__ bsum){
    __shared__ int wsum[16];
    const int t = threadIdx.x;
    const int idx = blockIdx.x*1024 + t;
    const int lane = t & 63, wid = t >> 6;
    int v = (idx < NN) ? cnt[idx] : 0;
    int s = v;
    #pragma unroll
    for (int o = 1; o < 64; o <<= 1){
        int u = __shfl_up(s, o, 64);
        if (lane >= o) s += u;
    }
    if (lane == 63) wsum[wid] = s;
    __syncthreads();
    if (wid == 0){
        int ws = (lane < 16) ? wsum[lane] : 0;
        #pragma unroll
        for (int o = 1; o < 16; o <<= 1){
            int u = __shfl_up(ws, o, 64);
            if (lane >= o) ws += u;
        }
        if (lane < 16) wsum[lane] = ws;
    }
    __syncthreads();
    int base = (wid > 0) ? wsum[wid-1] : 0;
    int incl = base + s;
    if (idx < NN) rowex[idx] = incl - v;
    if (t == 1023) bsum[blockIdx.x] = incl;
}

__global__ void scan_bsum(int* __restrict__ bsum, int nb){
    const int lane = threadIdx.x;
    int v = (lane < nb) ? bsum[lane] : 0;
    int s = v;
    #pragma unroll
    for (int o = 1; o < 64; o <<= 1){
        int u = __shfl_up(s, o, 64);
        if (lane >= o) s += u;
    }
    if (lane < nb) bsum[lane] = s - v;
}

__global__ void scan_fix(int* __restrict__ row, const int* __restrict__ bsum,
                         int* __restrict__ cursor){
    int idx = blockIdx.x*blockDim.x + threadIdx.x;
    if (idx < NN){
        int r = row[idx] + bsum[idx >> 10];
        row[idx] = r;
        cursor[idx] = r;
    }
    if (idx == 0) row[NN] = EE;
}

__global__ void fill_csr(const int* __restrict__ esrc, const int* __restrict__ edst,
                         int* __restrict__ cursor, int* __restrict__ adj,
                         int* __restrict__ dcsr){
    int i = blockIdx.x*blockDim.x + threadIdx.x;
    if (i >= EE) return;
    int d = edst[i];
    int slot = atomicAdd(&cursor[d], 1);
    adj[slot] = esrc[i];
    dcsr[slot] = d;
}

// ---------------- W pack: fp32 [K][M] -> bf16 B-fragment layout ----------------
__global__ void pack_w(const float* __restrict__ W, __hip_bfloat16* __restrict__ Wpk,
                       int K, int M){
    int i = blockIdx.x*blockDim.x + threadIdx.x;
    if (i >= K*M) return;
    int k = i / M, c = i - k*M;
    int kb = k >> 5, r = k & 31, quad = r >> 3, j = r & 7;
    int ct = c >> 4, ln = quad*16 + (c & 15);
    int CT = M >> 4;
    size_t dst = (((size_t)kb*CT + ct)*64 + ln)*8 + j;
    Wpk[dst] = __float2bfloat16(W[i]);
}

// ---------------- MFMA GEMM: H = bf16(X @ W), one wave per 16-node tile ------
template<int K, int M, bool AF32>
__global__ __launch_bounds__(256) void gemm_mfma(
        const void* __restrict__ Xv, const __hip_bfloat16* __restrict__ Wpk,
        __hip_bfloat16* __restrict__ Hb){
    constexpr int CT = M/16;
    constexpr int KB = K/32;
    const int wave = (blockIdx.x*256 + threadIdx.x) >> 6;
    const int lane = threadIdx.x & 63;
    const int n0 = wave*16;
    if (n0 >= NN) return;
    const int arow = lane & 15;
    const int quad = lane >> 4;

    f32x4 acc[CT];
    #pragma unroll
    for (int ct = 0; ct < CT; ++ct) acc[ct] = (f32x4){0.f,0.f,0.f,0.f};

    for (int kb = 0; kb < KB; ++kb){
        const int kbase = kb*32 + quad*8;
        short8 af;
        if constexpr (AF32){
            const float* ap = (const float*)Xv + (size_t)(n0 + arow)*K + kbase;
            float4 v0 = *(const float4*)ap;
            float4 v1 = *(const float4*)(ap + 4);
            af[0]=f2bs(v0.x); af[1]=f2bs(v0.y); af[2]=f2bs(v0.z); af[3]=f2bs(v0.w);
            af[4]=f2bs(v1.x); af[5]=f2bs(v1.y); af[6]=f2bs(v1.z); af[7]=f2bs(v1.w);
        } else {
            af = *(const short8*)((const __hip_bfloat16*)Xv + (size_t)(n0 + arow)*K + kbase);
        }
        const __hip_bfloat16* wp = Wpk + (size_t)kb*CT*64*8;
        #pragma unroll
        for (int ct = 0; ct < CT; ++ct){
            short8 bfr = *(const short8*)(wp + ((size_t)ct*64 + lane)*8);
            acc[ct] = __builtin_amdgcn_mfma_f32_16x16x32_bf16(af, bfr, acc[ct], 0, 0, 0);
        }
    }
    #pragma unroll
    for (int ct = 0; ct < CT; ++ct){
        #pragma unroll
        for (int r = 0; r < 4; ++r){
            int n = n0 + quad*4 + r;
            Hb[(size_t)n*M + ct*16 + arow] = __float2bfloat16(acc[ct][r]);
        }
    }
}

// ---------------- attention scores from bf16 H ----------------
template<int M, int F>
__global__ __launch_bounds__(M) void attn_scores(
        const __hip_bfloat16* __restrict__ Hb,
        const float* __restrict__ asrc, const float* __restrict__ adst,
        float* __restrict__ AS, float* __restrict__ AD){
    const int n = blockIdx.x, t = threadIdx.x;
    float h = __bfloat162float(Hb[(size_t)n*M + t]);
    float s1 = h*asrc[t], s2 = h*adst[t];
    #pragma unroll
    for (int o = F>>1; o > 0; o >>= 1){
        s1 += __shfl_down(s1, o, F);
        s2 += __shfl_down(s2, o, F);
    }
    if ((t & (F-1)) == 0){
        AS[(size_t)n*(M/F) + t/F] = s1;
        AD[(size_t)n*(M/F) + t/F] = s2;
    }
}

// ---------------- per-edge softmax weights (CSR slot order) ----------------
__global__ void edge_w4(const int* __restrict__ adj, const int* __restrict__ dcsr,
                        const float* __restrict__ AS, const float* __restrict__ AD,
                        float* __restrict__ wbuf){
    int i = blockIdx.x*blockDim.x + threadIdx.x;
    if (i >= EE) return;
    int s = adj[i], d = dcsr[i];
    float4 as = *(const float4*)(AS + (size_t)s*4);
    float4 ad = *(const float4*)(AD + (size_t)d*4);
    float4 w;
    w.x = expf(lrelu(as.x + ad.x));
    w.y = expf(lrelu(as.y + ad.y));
    w.z = expf(lrelu(as.z + ad.z));
    w.w = expf(lrelu(as.w + ad.w));
    *(float4*)(wbuf + (size_t)i*4) = w;
}

__global__ void edge_w1(const int* __restrict__ adj, const int* __restrict__ dcsr,
                        const float* __restrict__ AS, const float* __restrict__ AD,
                        float* __restrict__ wbuf){
    int i = blockIdx.x*blockDim.x + threadIdx.x;
    if (i >= EE) return;
    wbuf[i] = expf(lrelu(AS[adj[i]] + AD[dcsr[i]]));
}

// ---------------- atomic-free GAT aggregation, precomputed weights ----------
__global__ __launch_bounds__(64) void gat_agg_l1(
        const int* __restrict__ row, const int* __restrict__ adj,
        const float* __restrict__ wbuf,
        const __hip_bfloat16* __restrict__ Hfeat,
        const float* __restrict__ AS, const float* __restrict__ AD,
        const float* __restrict__ b, const float* __restrict__ p,
        __hip_bfloat16* __restrict__ outB){
    const int d = blockIdx.x;
    const int t = threadIdx.x;          // col pair t -> cols 2t, 2t+1
    const int h = t >> 4;               // 32 cols per head -> 16 threads per head
    const unsigned* Hw = (const unsigned*)Hfeat;
    float acc0 = 0.f, acc1 = 0.f, den = 0.f;
    {   // self loop
        float ws = expf(lrelu(AS[(size_t)d*4 + h] + AD[(size_t)d*4 + h]));
        unsigned u = Hw[(size_t)d*64 + t];
        acc0 += __uint_as_float(u << 16) * ws;
        acc1 += __uint_as_float(u & 0xffff0000u) * ws;
        den += ws;
    }
    const int beg = row[d], end = row[d+1];
    for (int j = beg; j < end; ++j){
        int s = adj[j];
        float wgt = wbuf[(size_t)j*4 + h];
        unsigned u = Hw[(size_t)s*64 + t];
        acc0 += __uint_as_float(u << 16) * wgt;
        acc1 += __uint_as_float(u & 0xffff0000u) * wgt;
        den += wgt;
    }
    float inv = 1.f/(den + 1e-16f);
    float v0 = acc0*inv + b[2*t];
    float v1 = acc1*inv + b[2*t+1];
    v0 = (v0 >= 0.f) ? v0 : p[2*t]*v0;
    v1 = (v1 >= 0.f) ? v1 : p[2*t+1]*v1;
    ushort2 st = make_ushort2((unsigned short)f2bs(v0), (unsigned short)f2bs(v1));
    *(ushort2*)(outB + (size_t)d*128 + 2*t) = st;
}

__global__ __launch_bounds__(64) void gat_agg_l2(
        const int* __restrict__ row, const int* __restrict__ adj,
        const float* __restrict__ wbuf,
        const __hip_bfloat16* __restrict__ Hfeat,
        const float* __restrict__ AS, const float* __restrict__ AD,
        const float* __restrict__ b, const float* __restrict__ p,
        float* __restrict__ outF){
    const int d = blockIdx.x;
    const int t = threadIdx.x;
    float acc = 0.f, den = 0.f;
    {   // self loop
        float ws = expf(lrelu(AS[d] + AD[d]));
        acc += __bfloat162float(Hfeat[(size_t)d*64 + t]) * ws;
        den += ws;
    }
    const int beg = row[d], end = row[d+1];
    for (int j = beg; j < end; ++j){
        int s = adj[j];
        float wgt = wbuf[j];
        acc += __bfloat162float(Hfeat[(size_t)s*64 + t]) * wgt;
        den += wgt;
    }
    float v = acc/(den + 1e-16f) + b[t];
    outF[(size_t)d*64 + t] = (v >= 0.f) ? v : p[t]*v;
}

// ---------------- coalesced column sums ----------------
__global__ __launch_bounds__(256) void colsum_fast(const float* __restrict__ X,
                                                   float* __restrict__ out){
    __shared__ float red[256];
    const int t = threadIdx.x;
    const int c = t & 63;
    const int rg = t >> 6;
    float s = 0.f;
    for (int r = blockIdx.x*4 + rg; r < NN; r += gridDim.x*4)
        s += X[(size_t)r*64 + c];
    red[t] = s; __syncthreads();
    if (t < 64){
        float v = red[t] + red[t+64] + red[t+128] + red[t+192];
        atomicAdd(&out[c], v);
    }
}

__global__ void summary(const float* __restrict__ csum_o, const float* __restrict__ csum_a,
                        const float* __restrict__ mlpW, const float* __restrict__ mlpb,
                        const float* __restrict__ discW,
                        const float* __restrict__ advW, const float* __restrict__ advb,
                        float* __restrict__ Wc_o, float* __restrict__ Wc_a,
                        float* __restrict__ advRow, float* __restrict__ advbsum){
    __shared__ float s_o[64], s_a[64], h_o[64], h_a[64];
    const int t = threadIdx.x;
    s_o[t] = 1.f/(1.f + expf(-csum_o[t]/(float)NN));
    s_a[t] = 1.f/(1.f + expf(-csum_a[t]/(float)NN));
    __syncthreads();
    float ao = 0.f, aa = 0.f;
    for (int k = 0; k < 64; ++k){ float w = mlpW[k*64 + t]; ao += s_o[k]*w; aa += s_a[k]*w; }
    float bb = mlpb[t];
    h_o[t] = ao + bb; h_a[t] = aa + bb;
    __syncthreads();
    float wo = 0.f, wa = 0.f;
    for (int j = 0; j < 64; ++j){ float w = discW[t*64 + j]; wo += w*h_o[j]; wa += w*h_a[j]; }
    Wc_o[t] = wo; Wc_a[t] = wa;
    float ar = 0.f;
    for (int j = 0; j < 64; ++j) ar += advW[t*64 + j];
    advRow[t] = ar;
    float ab = advb[t];
    for (int o = 32; o > 0; o >>= 1) ab += __shfl_down(ab, o, 64);
    if (t == 0) advbsum[0] = ab;
}

__global__ void node_outputs(const float* __restrict__ x2o, const float* __restrict__ x2a,
                             const float* __restrict__ Wc_o, const float* __restrict__ Wc_a,
                             const float* __restrict__ advRow, const float* __restrict__ advbsum,
                             const float* __restrict__ discb,
                             float* __restrict__ out){
    const int n = blockIdx.x*4 + (threadIdx.x >> 6);
    const int l = threadIdx.x & 63;
    float xo = x2o[(size_t)n*64 + l], xa = x2a[(size_t)n*64 + l];
    float wo = Wc_o[l], wa = Wc_a[l], ar = advRow[l];
    float d1 = xo*wo, d2 = xa*wo, d3 = xa*wa, d4 = xo*wa, d5 = xo*ar, d6 = xa*ar;
    for (int o = 32; o > 0; o >>= 1){
        d1 += __shfl_down(d1, o, 64); d2 += __shfl_down(d2, o, 64);
        d3 += __shfl_down(d3, o, 64); d4 += __shfl_down(d4, o, 64);
        d5 += __shfl_down(d5, o, 64); d6 += __shfl_down(d6, o, 64);
    }
    out[O_X2 + (size_t)n*64 + l] = xo;
    if (l == 0){
        float db = discb[0];
        float ab = advbsum[0];
        out[O_RETOS  + n*2 + 0] = d1 + db;
        out[O_RETOS  + n*2 + 1] = d2 + db;
        out[O_RETOSA + n*2 + 0] = d3 + db;
        out[O_RETOSA + n*2 + 1] = d4 + db;
        out[O_LOGITS + n]       = d5 + ab;
        out[O_LOGITS + NN + n]  = d6 + ab;
    }
}

// ---------------- fused decoder: MFMA fh + both heads, 16 pairs/block --------
// Wave w of 4 handles cols [w*128, w*128+128). A = [x2o[i0] | x2o[i1]] (fp32->bf16
// in flight; k-blocks 0-1 from i0, 2-3 from i1). B = fW1 packed bf16.
// Epilogue: v=relu(acc+fb1); per-lane dot with fW2/fW3 cols; width-16 quad
// reduce; LDS cross-wave fold; direct store of log/log1.
__global__ __launch_bounds__(256) void decoder_fused(
        const float* __restrict__ x2o, const int* __restrict__ idxArr,
        const __hip_bfloat16* __restrict__ Wpkf, const float* __restrict__ fb1,
        const float* __restrict__ fW2, const float* __restrict__ fb2,
        const float* __restrict__ fW3, const float* __restrict__ fb3,
        float* __restrict__ out){
    __shared__ float part[4][16][4];
    const int t = threadIdx.x;
    const int wid = t >> 6, lane = t & 63;
    const int arow = lane & 15, quad = lane >> 4;
    const int p0 = blockIdx.x*16;
    const int i0 = idxArr[p0 + arow];
    const int i1 = idxArr[BP + p0 + arow];

    f32x4 acc[8];
    #pragma unroll
    for (int c = 0; c < 8; ++c) acc[c] = (f32x4){0.f,0.f,0.f,0.f};

    #pragma unroll
    for (int kb = 0; kb < 4; ++kb){
        int src = (kb < 2) ? i0 : i1;
        int koff = (kb & 1)*32 + quad*8;
        const float* ap = x2o + (size_t)src*64 + koff;
        float4 v0 = *(const float4*)ap;
        float4 v1 = *(const float4*)(ap + 4);
        short8 af;
        af[0]=f2bs(v0.x); af[1]=f2bs(v0.y); af[2]=f2bs(v0.z); af[3]=f2bs(v0.w);
        af[4]=f2bs(v1.x); af[5]=f2bs(v1.y); af[6]=f2bs(v1.z); af[7]=f2bs(v1.w);
        const __hip_bfloat16* wp = Wpkf + (size_t)kb*32*64*8;
        #pragma unroll
        for (int c = 0; c < 8; ++c){
            int ct = wid*8 + c;
            short8 bfr = *(const short8*)(wp + ((size_t)ct*64 + lane)*8);
            acc[c] = __builtin_amdgcn_mfma_f32_16x16x32_bf16(af, bfr, acc[c], 0, 0, 0);
        }
    }

    float a0[4] = {0,0,0,0}, a1[4] = {0,0,0,0};
    float c0[4] = {0,0,0,0}, c1[4] = {0,0,0,0};
    #pragma unroll
    for (int c = 0; c < 8; ++c){
        int col = wid*128 + c*16 + arow;
        float bb = fb1[col];
        float w20 = fW2[col*2], w21 = fW2[col*2+1];
        float w30 = fW3[col*2], w31 = fW3[col*2+1];
        #pragma unroll
        for (int r = 0; r < 4; ++r){
            float v = acc[c][r] + bb;
            v = (v > 0.f) ? v : 0.f;
            a0[r] += v*w20; a1[r] += v*w21;
            c0[r] += v*w30; c1[r] += v*w31;
        }
    }
    #pragma unroll
    for (int o = 8; o > 0; o >>= 1){
        #pragma unroll
        for (int r = 0; r < 4; ++r){
            a0[r] += __shfl_down(a0[r], o, 16);
            a1[r] += __shfl_down(a1[r], o, 16);
            c0[r] += __shfl_down(c0[r], o, 16);
            c1[r] += __shfl_down(c1[r], o, 16);
        }
    }
    if (arow == 0){
        #pragma unroll
        for (int r = 0; r < 4; ++r){
            part[wid][quad*4 + r][0] = a0[r];
            part[wid][quad*4 + r][1] = a1[r];
            part[wid][quad*4 + r][2] = c0[r];
            part[wid][quad*4 + r][3] = c1[r];
        }
    }
    __syncthreads();
    if (t < 64){
        int pr = t >> 2, o = t & 3;
        float s = part[0][pr][o] + part[1][pr][o] + part[2][pr][o] + part[3][pr][o];
        int gb = p0 + pr;
        if (o == 0)      out[O_LOG  + gb*2 + 0] = s + fb2[0];
        else if (o == 1) out[O_LOG  + gb*2 + 1] = s + fb2[1];
        else if (o == 2) out[O_LOG1 + gb*2 + 0] = s + fb3[0];
        else             out[O_LOG1 + gb*2 + 1] = s + fb3[1];
    }
}

extern "C" void kernel_launch(void* const* d_in, const int* in_sizes, int n_in,
                              void* d_out, int out_size, void* d_ws, size_t ws_size,
                              hipStream_t stream){
    const float* x_o    = (const float*)d_in[0];
    const float* x_a    = (const float*)d_in[1];
    const int*   edge   = (const int*)d_in[2];
    const int*   idxp   = (const int*)d_in[3];
    const float* W1     = (const float*)d_in[4];
    const float* a_src1 = (const float*)d_in[5];
    const float* a_dst1 = (const float*)d_in[6];
    const float* b1     = (const float*)d_in[7];
    const float* p1     = (const float*)d_in[8];
    const float* W2     = (const float*)d_in[9];
    const float* a_src2 = (const float*)d_in[10];
    const float* a_dst2 = (const float*)d_in[11];
    const float* b2     = (const float*)d_in[12];
    const float* p2     = (const float*)d_in[13];
    const float* mlpW   = (const float*)d_in[14];
    const float* mlpb   = (const float*)d_in[15];
    const float* discW  = (const float*)d_in[16];
    const float* discb  = (const float*)d_in[17];
    const float* advW   = (const float*)d_in[18];
    const float* advb   = (const float*)d_in[19];
    const float* fW1    = (const float*)d_in[20];
    const float* fb1    = (const float*)d_in[21];
    const float* fW2    = (const float*)d_in[22];
    const float* fb2    = (const float*)d_in[23];
    const float* fW3    = (const float*)d_in[24];
    const float* fb3    = (const float*)d_in[25];

    const int* esrc = edge;
    const int* edst = edge + EE;

    // workspace carve-up (fp32 units), ~70 MB total
    float* w = (float*)d_ws;
    size_t off = 0;
    auto alloc = [&](size_t nfloats){ float* p = w + off; off += nfloats; return p; };
    __hip_bfloat16* Hb   = (__hip_bfloat16*)alloc((size_t)NN*M1/2);
    __hip_bfloat16* x1b  = (__hip_bfloat16*)alloc((size_t)NN*M1/2);
    float* asb   = alloc((size_t)NN*H1N);
    float* adb   = alloc((size_t)NN*H1N);
    float* x2o   = alloc((size_t)NN*M2);
    float* x2a   = alloc((size_t)NN*M2);
    float* wbuf  = alloc((size_t)EE*H1N);
    __hip_bfloat16* Wpk1 = (__hip_bfloat16*)alloc((size_t)DIN*M1/2);
    __hip_bfloat16* Wpk2 = (__hip_bfloat16*)alloc((size_t)M1*M2/2);
    __hip_bfloat16* Wpkf = (__hip_bfloat16*)alloc((size_t)M1*DEC/2);
    int*   cnt   = (int*)alloc(NN);
    int*   row   = (int*)alloc(NN + 1);
    int*   cursor= (int*)alloc(NN);
    int*   adj   = (int*)alloc(EE);
    int*   dcsr  = (int*)alloc(EE);
    int*   bsum  = (int*)alloc(SCAN_NB + 1);
    float* smallb= alloc(512);
    float* csum_o = smallb;       float* csum_a = smallb + 64;
    float* Wc_o   = smallb + 128; float* Wc_a   = smallb + 192;
    float* advRow = smallb + 256; float* advbs  = smallb + 320;

    float* out = (float*)d_out;

    // ---- CSR build + W packing (once) ----
    hipMemsetAsync(cnt, 0, NN*sizeof(int), stream);
    hipMemsetAsync(smallb, 0, 128*sizeof(float), stream);
    hist_dst<<<(EE + 255)/256, 256, 0, stream>>>(edst, cnt);
    scan_blk<<<SCAN_NB, 1024, 0, stream>>>(cnt, row, bsum);
    scan_bsum<<<1, 64, 0, stream>>>(bsum, SCAN_NB);
    scan_fix<<<(NN + 255)/256, 256, 0, stream>>>(row, bsum, cursor);
    fill_csr<<<(EE + 255)/256, 256, 0, stream>>>(esrc, edst, cursor, adj, dcsr);
    pack_w<<<(DIN*M1 + 255)/256, 256, 0, stream>>>(W1, Wpk1, DIN, M1);
    pack_w<<<(M1*M2 + 255)/256, 256, 0, stream>>>(W2, Wpk2, M1, M2);
    pack_w<<<(M1*DEC + 255)/256, 256, 0, stream>>>(fW1, Wpkf, M1, DEC);

    const int gw = ((NN/16) + 3) / 4;
    const int ge = (EE + 255)/256;

    auto run_encoder = [&](const float* xin, float* x2out){
        gemm_mfma<DIN, M1, true><<<gw, 256, 0, stream>>>(xin, Wpk1, Hb);
        attn_scores<M1, F1><<<NN, M1, 0, stream>>>(Hb, a_src1, a_dst1, asb, adb);
        edge_w4<<<ge, 256, 0, stream>>>(adj, dcsr, asb, adb, wbuf);
        gat_agg_l1<<<NN, 64, 0, stream>>>(row, adj, wbuf, Hb, asb, adb, b1, p1, x1b);

        gemm_mfma<M1, M2, false><<<gw, 256, 0, stream>>>(x1b, Wpk2, Hb);
        attn_scores<M2, M2><<<NN, M2, 0, stream>>>(Hb, a_src2, a_dst2, asb, adb);
        edge_w1<<<ge, 256, 0, stream>>>(adj, dcsr, asb, adb, wbuf);
        gat_agg_l2<<<NN, 64, 0, stream>>>(row, adj, wbuf, Hb, asb, adb, b2, p2, x2out);
    };

    run_encoder(x_o, x2o);
    run_encoder(x_a, x2a);

    colsum_fast<<<256, 256, 0, stream>>>(x2o, csum_o);
    colsum_fast<<<256, 256, 0, stream>>>(x2a, csum_a);
    summary<<<1, 64, 0, stream>>>(csum_o, csum_a, mlpW, mlpb, discW, advW, advb,
                                  Wc_o, Wc_a, advRow, advbs);
    node_outputs<<<NN/4, 256, 0, stream>>>(x2o, x2a, Wc_o, Wc_a, advRow, advbs, discb, out);
    decoder_fused<<<BP/16, 256, 0, stream>>>(x2o, idxp, Wpkf, fb1, fW2, fb2, fW3, fb3, out);
}